// Round 6
// baseline (2110.796 us; speedup 1.0000x reference)
//
#include <hip/hip_runtime.h>

typedef __attribute__((ext_vector_type(4))) float f32x4;
typedef __attribute__((ext_vector_type(8))) short s16x8;

// ---- LDS layout (byte offsets), total 73728 B -> 2 blocks/CU ----
#define L_XW   0        // bf16 [64][256] swz, stride 512B  (later: H chunk, mlp bf16)
#define L_QK   32768    // bf16 [2][64][64] (q cols 0-31 | k cols 32-63), stride 128B/row
#define L_VT   49152    // bf16 [2][32][64] v transposed, stride 128B
#define L_P    57344    // bf16 [2][64][128B-rows]; O-slice ALIASED into bytes 64..127 of each row
#define L_Y    32768    // bf16 [64][256] swz, stride 512B (aliases QK/VT/P[0] after attention)
#define L_H    0        // bf16 [64][256] (aliases XW after LN1)
#define L_MB   0        // bf16 [64][256] mlp pre-LN (aliases H after fc2)
#define SMEM_BYTES 73728

// ---- workspace layout (byte offsets) ----
#define WSO_BIAS   0          // f32 [8][64][16][4] packed (h,i,c16,nt)   131072 B
#define WSO_QKVW   131072     // bf16 [48][32][16][8]       393216 B
#define WSO_PROJW  524288     // bf16 [16][32][16][8]       131072 B
#define WSO_FC1W   655360     // bf16 [64][32][16][8]       524288 B
#define WSO_FC2W   1179648    // bf16 [16][128][16][8]      524288 B
#define WSO_SIN    1703936ULL // bf16 [2][65536][256]       67108864 B
#define WSO_SOUT   68812800ULL// bf16 [2][65536][256]       67108864 B

__device__ __forceinline__ unsigned short f2bf(float f) {
  union { float f; unsigned u; } v; v.f = f;
  unsigned r = v.u + 0x7FFFu + ((v.u >> 16) & 1u);
  return (unsigned short)(r >> 16);
}
__device__ __forceinline__ float bf2f(unsigned short b) {
  union { unsigned u; float f; } v; v.u = ((unsigned)b) << 16;
  return v.f;
}
__device__ __forceinline__ int swzb(int row, int byteoff) {  // for rows >=128B
  return byteoff ^ ((row & 7) << 4);
}
__device__ __forceinline__ int swz64(int row, int byteoff) { // for 64B sub-rows
  return byteoff ^ ((row & 3) << 4);
}
// O-slice lives in bytes 64..127 of P row i (safe: each (hh,wm) wave reads its own
// 16-row P slice fully -- both k0 steps -- before writing its O-slice there)
__device__ __forceinline__ int osb(int hh, int i, int byteoff) {
  return L_P + hh * 8192 + i * 128 + 64 + swz64(i, byteoff);
}

// ---------------- prep: pack all weights to bf16 MFMA-fragment layout ----------------
__global__ void prep_pack_kernel(const float* __restrict__ qkv_w,
                                 const float* __restrict__ proj_w,
                                 const float* __restrict__ fc1_w,
                                 const float* __restrict__ fc2_w,
                                 unsigned char* __restrict__ wsb) {
  int e = blockIdx.x * 256 + threadIdx.x;   // 0 .. 786431
  const float* src; unsigned short* dst; int K, N; int eo;
  if (e < 196608)       { eo = e;          src = qkv_w;  dst = (unsigned short*)(wsb + WSO_QKVW);  K = 256;  N = 768; }
  else if (e < 262144)  { eo = e - 196608; src = proj_w; dst = (unsigned short*)(wsb + WSO_PROJW); K = 256;  N = 256; }
  else if (e < 524288)  { eo = e - 262144; src = fc1_w;  dst = (unsigned short*)(wsb + WSO_FC1W);  K = 256;  N = 1024; }
  else                  { eo = e - 524288; src = fc2_w;  dst = (unsigned short*)(wsb + WSO_FC2W);  K = 1024; N = 256; }
  int j = eo & 7, c = (eo >> 3) & 15, rest = eo >> 7;
  int Kg = K >> 3;
  int kg = rest % Kg, nt = rest / Kg;
  dst[eo] = f2bf(src[(kg * 8 + j) * N + nt * 16 + c]);
}

// ---------------- prep: relative-position-bias table via CPB MLP (packed float4) ----------------
__global__ void prep_bias_kernel(const float* __restrict__ cpb_w1,
                                 const float* __restrict__ cpb_b1,
                                 const float* __restrict__ cpb_w2,
                                 unsigned char* __restrict__ wsb) {
  __shared__ float bt[225][8];
  int tid = threadIdx.x;
  for (int t = tid; t < 225; t += 256) {
    int a = t / 15, b = t % 15;
    float r0 = (float)(a - 7) * (8.0f / 7.0f);
    float r1 = (float)(b - 7) * (8.0f / 7.0f);
    float f0 = (r0 >= 0.f ? 1.f : -1.f) * log2f(fabsf(r0) + 1.f) * (1.f / 3.f);
    float f1 = (r1 >= 0.f ? 1.f : -1.f) * log2f(fabsf(r1) + 1.f) * (1.f / 3.f);
    float acc[8] = {0.f,0.f,0.f,0.f,0.f,0.f,0.f,0.f};
    for (int k = 0; k < 512; ++k) {
      float hv = f0 * cpb_w1[k] + f1 * cpb_w1[512 + k] + cpb_b1[k];
      hv = fmaxf(hv, 0.f);
      #pragma unroll
      for (int h = 0; h < 8; ++h) acc[h] += hv * cpb_w2[k * 8 + h];
    }
    #pragma unroll
    for (int h = 0; h < 8; ++h) bt[t][h] = acc[h];
  }
  __syncthreads();
  float* biasp = (float*)(wsb + WSO_BIAS);
  for (int e = tid; e < 32768; e += 256) {
    int nn = e & 3, cc = (e >> 2) & 15, i = (e >> 6) & 63, h = e >> 12;
    int j = nn * 16 + cc;
    int dr = (i >> 3) - (j >> 3) + 7, dc = (i & 7) - (j & 7) + 7;
    float v = bt[dr * 15 + dc][h];
    biasp[e] = 16.f / (1.f + expf(-v));
  }
}

// ---------------- pass A: x[b][c][p] f32 -> sin[b][p][c] bf16 (tiled transpose) ----------------
__global__ __launch_bounds__(256)
void transpose_in_kernel(const float* __restrict__ x, unsigned char* __restrict__ wsb) {
  __shared__ float tile[64][65];
  int pb = blockIdx.x & 1023;
  int cg = (blockIdx.x >> 10) & 3;
  int b  = blockIdx.x >> 12;
  int p0 = pb * 64, c0 = cg * 64;
  int tid = threadIdx.x;
  unsigned short* sg = (unsigned short*)(wsb + WSO_SIN);

  int pi = tid & 63, cq = tid >> 6;
  for (int r = 0; r < 16; ++r) {
    int c = cq * 16 + r;
    tile[pi][c] = x[((size_t)(b * 256 + c0 + c)) * 65536 + p0 + pi];
  }
  __syncthreads();
  int po = tid >> 2, co = tid & 3;
  s16x8 pk0, pk1;
  #pragma unroll
  for (int j = 0; j < 8; ++j) {
    pk0[j] = (short)f2bf(tile[po][co * 16 + j]);
    pk1[j] = (short)f2bf(tile[po][co * 16 + 8 + j]);
  }
  unsigned short* dp = sg + ((size_t)b * 65536 + p0 + po) * 256 + c0 + co * 16;
  *(s16x8*)(dp) = pk0;
  *(s16x8*)(dp + 8) = pk1;
}

// ---------------- pass B: sout[b][p][c] bf16 -> out[b][c][p] f32 (tiled transpose) ----------------
__global__ __launch_bounds__(256)
void transpose_out_kernel(const unsigned char* __restrict__ wsb, float* __restrict__ out) {
  __shared__ float tile[64][65];
  int pb = blockIdx.x & 1023;
  int cg = (blockIdx.x >> 10) & 3;
  int b  = blockIdx.x >> 12;
  int p0 = pb * 64, c0 = cg * 64;
  int tid = threadIdx.x;
  const unsigned short* sg = (const unsigned short*)(wsb + WSO_SOUT);

  int pi = tid >> 2, cq = tid & 3;
  const unsigned short* rp = sg + ((size_t)b * 65536 + p0 + pi) * 256 + c0 + cq * 16;
  s16x8 a0 = *(const s16x8*)(rp);
  s16x8 a1 = *(const s16x8*)(rp + 8);
  #pragma unroll
  for (int j = 0; j < 8; ++j) {
    tile[pi][cq * 16 + j]     = bf2f((unsigned short)a0[j]);
    tile[pi][cq * 16 + 8 + j] = bf2f((unsigned short)a1[j]);
  }
  __syncthreads();
  int ci = tid >> 6, pi2 = tid & 63;
  for (int r = 0; r < 16; ++r) {
    int c = ci * 16 + r;
    out[((size_t)(b * 256 + c0 + c)) * 65536 + p0 + pi2] = tile[pi2][c];
  }
}

// ---------------- main fused per-window kernel: 512 threads / 8 waves ----------------
// __launch_bounds__(512,4): VGPR cap 128 (round-5 evidence: demand fits exactly, no spill)
// + 72KB LDS -> 2 independent blocks/CU (16 waves/CU, 4 waves/SIMD) so one block's
// compute covers the other block's barrier drains.
__global__ __launch_bounds__(512, 4)
void swin_block_kernel(const float* __restrict__ ls,
                       const float* __restrict__ proj_b,
                       const float* __restrict__ ln1w, const float* __restrict__ ln1b,
                       const float* __restrict__ fc1b,
                       const float* __restrict__ fc2b,
                       const float* __restrict__ ln2w, const float* __restrict__ ln2b,
                       unsigned char* __restrict__ wsb) {
  extern __shared__ char sm[];
  const int tid = threadIdx.x;
  const int w = tid >> 6;
  const int lane = tid & 63;
  const int g = lane >> 4;
  const int c16 = lane & 15;
  const int mh = w & 1;
  const int nq = w >> 1;

  const int blk = blockIdx.x;
  const int bb = blk >> 10;
  const int widx = blk & 1023;
  const int wi = widx >> 5, wj = widx & 31;

  const f32x4* biasv = (const f32x4*)(wsb + WSO_BIAS);
  const unsigned short* qkvw = (const unsigned short*)(wsb + WSO_QKVW);
  const unsigned short* projw = (const unsigned short*)(wsb + WSO_PROJW);
  const unsigned short* fc1w = (const unsigned short*)(wsb + WSO_FC1W);
  const unsigned short* fc2w = (const unsigned short*)(wsb + WSO_FC2W);
  const unsigned short* sin_ = (const unsigned short*)(wsb + WSO_SIN);
  unsigned short* sout = (unsigned short*)(wsb + WSO_SOUT);

  // ---------- Phase 1: copy window from sin (channel-contiguous) -> XW bf16 swz ----------
  #pragma unroll
  for (int it = 0; it < 4; ++it) {
    int u = tid + it * 512;              // 16B units: u = t*32 + cu
    int t = u >> 5, cu = u & 31;
    int rp = (wi * 8 + (t >> 3) + 4) & 255;
    int cp = (wj * 8 + (t & 7) + 4) & 255;
    size_t pix = (size_t)bb * 65536 + rp * 256 + cp;
    s16x8 v = *(const s16x8*)(sin_ + pix * 256 + cu * 8);
    *(s16x8*)(sm + L_XW + t * 512 + swzb(t, cu * 16)) = v;
  }
  __syncthreads();

  // persistent proj accumulator: wave (mh,nq) owns rows 32mh..+31, cols nq*64..+63
  f32x4 accP[4][2];
  #pragma unroll
  for (int a = 0; a < 4; ++a)
    #pragma unroll
    for (int b = 0; b < 2; ++b) accP[a][b] = f32x4{0.f,0.f,0.f,0.f};

  // ---------- attention (+fused proj) per head pair ----------
  #pragma unroll 1
  for (int hp = 0; hp < 4; ++hp) {
    // qkv GEMM: 12 N-tiles; wave (mh,nq) -> locals nq*3..nq*3+2, m-tiles 2mh..2mh+1
    f32x4 acc[3][2];
    #pragma unroll
    for (int a = 0; a < 3; ++a)
      #pragma unroll
      for (int b = 0; b < 2; ++b) acc[a][b] = f32x4{0.f,0.f,0.f,0.f};
    int gtile[3];
    #pragma unroll
    for (int tl = 0; tl < 3; ++tl) {
      int local = nq * 3 + tl;
      int kind = local >> 2, sub = local & 3;
      int hh = sub >> 1, dt = sub & 1;
      gtile[tl] = kind * 16 + (2 * hp + hh) * 2 + dt;
    }
    for (int k0 = 0; k0 < 256; k0 += 32) {
      s16x8 af[2];
      #pragma unroll
      for (int j = 0; j < 2; ++j) {
        int row = (2 * mh + j) * 16 + c16;
        af[j] = *(const s16x8*)(sm + L_XW + row * 512 + swzb(row, (k0 + g * 8) * 2));
      }
      #pragma unroll
      for (int tl = 0; tl < 3; ++tl) {
        s16x8 bfr = *(const s16x8*)(qkvw + ((gtile[tl] * 32 + (k0 >> 3) + g) * 16 + c16) * 8);
        #pragma unroll
        for (int j = 0; j < 2; ++j)
          acc[tl][j] = __builtin_amdgcn_mfma_f32_16x16x32_bf16(af[j], bfr, acc[tl][j], 0, 0, 0);
      }
    }
    // epilogue: q,k -> QK[hh]; v -> VT[hh] transposed
    #pragma unroll
    for (int tl = 0; tl < 3; ++tl) {
      int local = nq * 3 + tl;
      int kind = local >> 2, sub = local & 3;
      int hh = sub >> 1, dt = sub & 1;
      #pragma unroll
      for (int j = 0; j < 2; ++j)
        #pragma unroll
        for (int r = 0; r < 4; ++r) {
          int i = (2 * mh + j) * 16 + 4 * g + r;
          unsigned short bv = f2bf(acc[tl][j][r]);
          if (kind == 0) {
            *(unsigned short*)(sm + L_QK + hh * 8192 + i * 128 + swzb(i, (dt * 16 + c16) * 2)) = bv;
          } else if (kind == 1) {
            *(unsigned short*)(sm + L_QK + hh * 8192 + i * 128 + swzb(i, 64 + (dt * 16 + c16) * 2)) = bv;
          } else {
            int d = dt * 16 + c16;
            *(unsigned short*)(sm + L_VT + hh * 4096 + d * 128 + swzb(d, i * 2)) = bv;
          }
        }
    }
    __syncthreads();   // B0

    // cosine-normalize q (with logit scale) and k, in place; thread = (hh,qi,row,half): 16 vals
    {
      int hh2 = tid >> 8, qi = (tid >> 7) & 1, t = (tid >> 1) & 63, hf = tid & 1;
      char* base = sm + L_QK + hh2 * 8192 + t * 128;
      float vals[16];
      float ss = 0.f;
      #pragma unroll
      for (int b = 0; b < 2; ++b) {
        s16x8 vb = *(const s16x8*)(base + swzb(t, qi * 64 + (hf * 2 + b) * 16));
        #pragma unroll
        for (int e = 0; e < 8; ++e) { float fv = bf2f((unsigned short)vb[e]); vals[b*8+e] = fv; ss += fv * fv; }
      }
      ss += __shfl_xor(ss, 1);          // pair with other half of the row
      float scale = 1.f;
      if (qi == 0) scale = __expf(fminf(ls[2 * hp + hh2], 4.6051702f));
      float inv = scale / fmaxf(sqrtf(ss), 1e-12f);
      #pragma unroll
      for (int b = 0; b < 2; ++b) {
        s16x8 vb;
        #pragma unroll
        for (int e = 0; e < 8; ++e) vb[e] = (short)f2bf(vals[b*8+e] * inv);
        *(s16x8*)(base + swzb(t, qi * 64 + (hf * 2 + b) * 16)) = vb;
      }
    }
    __syncthreads();   // Bn

    // ----- S + softmax + PV: both heads in parallel (hh = w>>2, wm = w&3) -----
    {
      const int hh = w >> 2;
      const int wm = w & 3;
      const int h = 2 * hp + hh;
      f32x4 bb4[4];
      #pragma unroll
      for (int r = 0; r < 4; ++r) {
        int i = 16 * wm + 4 * g + r;
        bb4[r] = biasv[(h * 64 + i) * 16 + c16];
      }
      int arow = 16 * wm + c16;
      s16x8 aq = *(const s16x8*)(sm + L_QK + hh * 8192 + arow * 128 + swzb(arow, g * 16));
      f32x4 s[4];
      #pragma unroll
      for (int nt = 0; nt < 4; ++nt) {
        int brow = nt * 16 + c16;
        s16x8 bk = *(const s16x8*)(sm + L_QK + hh * 8192 + brow * 128 + swzb(brow, 64 + g * 16));
        s[nt] = __builtin_amdgcn_mfma_f32_16x16x32_bf16(aq, bk, f32x4{0.f,0.f,0.f,0.f}, 0, 0, 0);
      }
      int labi[4], labj[4];
      #pragma unroll
      for (int r = 0; r < 4; ++r) {
        int i = 16 * wm + 4 * g + r;
        int tr = i >> 3, tc = i & 7;
        labi[r] = ((wi == 31) ? (tr >= 4 ? 2 : 1) : 0) * 3 + ((wj == 31) ? (tc >= 4 ? 2 : 1) : 0);
      }
      #pragma unroll
      for (int nt = 0; nt < 4; ++nt) {
        int jj = nt * 16 + c16;
        int tr = jj >> 3, tc = jj & 7;
        labj[nt] = ((wi == 31) ? (tr >= 4 ? 2 : 1) : 0) * 3 + ((wj == 31) ? (tc >= 4 ? 2 : 1) : 0);
      }
      float p[4][4];
      #pragma unroll
      for (int r = 0; r < 4; ++r) {
        float mx = -1e30f;
        float vv[4];
        #pragma unroll
        for (int nt = 0; nt < 4; ++nt) {
          float v = s[nt][r] + bb4[r][nt];
          if (labi[r] != labj[nt]) v -= 100.f;
          vv[nt] = v;
          mx = fmaxf(mx, v);
        }
        mx = fmaxf(mx, __shfl_xor(mx, 1));
        mx = fmaxf(mx, __shfl_xor(mx, 2));
        mx = fmaxf(mx, __shfl_xor(mx, 4));
        mx = fmaxf(mx, __shfl_xor(mx, 8));
        float sum = 0.f;
        #pragma unroll
        for (int nt = 0; nt < 4; ++nt) { vv[nt] = __expf(vv[nt] - mx); sum += vv[nt]; }
        sum += __shfl_xor(sum, 1);
        sum += __shfl_xor(sum, 2);
        sum += __shfl_xor(sum, 4);
        sum += __shfl_xor(sum, 8);
        float inv = 1.f / sum;
        #pragma unroll
        for (int nt = 0; nt < 4; ++nt) p[nt][r] = vv[nt] * inv;
      }
      #pragma unroll
      for (int nt = 0; nt < 4; ++nt)
        #pragma unroll
        for (int r = 0; r < 4; ++r) {
          int i = 16 * wm + 4 * g + r;
          int jj = nt * 16 + c16;
          *(unsigned short*)(sm + L_P + hh * 8192 + i * 128 + swzb(i, jj * 2)) = f2bf(p[nt][r]);
        }
      __syncthreads();   // B1: P complete

      f32x4 oacc[2] = {f32x4{0.f,0.f,0.f,0.f}, f32x4{0.f,0.f,0.f,0.f}};
      #pragma unroll
      for (int k0 = 0; k0 < 64; k0 += 32) {
        int prow = 16 * wm + c16;
        s16x8 pa = *(const s16x8*)(sm + L_P + hh * 8192 + prow * 128 + swzb(prow, (k0 + g * 8) * 2));
        #pragma unroll
        for (int nt = 0; nt < 2; ++nt) {
          int vrow = nt * 16 + c16;
          s16x8 vb = *(const s16x8*)(sm + L_VT + hh * 4096 + vrow * 128 + swzb(vrow, (k0 + g * 8) * 2));
          oacc[nt] = __builtin_amdgcn_mfma_f32_16x16x32_bf16(pa, vb, oacc[nt], 0, 0, 0);
        }
      }
      // O-slice store: aliased into bytes 64..127 of this wave's own P rows
      // (all P reads of these rows completed above, same wave, in-order DS pipe)
      #pragma unroll
      for (int nt = 0; nt < 2; ++nt)
        #pragma unroll
        for (int r = 0; r < 4; ++r) {
          int i = 16 * wm + 4 * g + r;
          int d = nt * 16 + c16;
          *(unsigned short*)(sm + osb(hh, i, d * 2)) = f2bf(oacc[nt][r]);
        }
      __syncthreads();   // B2: O slices complete
    }

    // fused proj partial: accP += O_slice @ projw, K=64 (both heads), wave (mh,nq)
    #pragma unroll
    for (int hh2 = 0; hh2 < 2; ++hh2) {
      int h = 2 * hp + hh2;
      s16x8 paf[2];
      #pragma unroll
      for (int j = 0; j < 2; ++j) {
        int row = (2 * mh + j) * 16 + c16;
        paf[j] = *(const s16x8*)(sm + osb(hh2, row, g * 16));
      }
      #pragma unroll
      for (int nt = 0; nt < 4; ++nt) {
        s16x8 bfr = *(const s16x8*)(projw + (((nq * 4 + nt) * 32 + h * 4 + g) * 16 + c16) * 8);
        #pragma unroll
        for (int j = 0; j < 2; ++j)
          accP[nt][j] = __builtin_amdgcn_mfma_f32_16x16x32_bf16(paf[j], bfr, accP[nt][j], 0, 0, 0);
      }
    }
  }
  __syncthreads();   // protect Y writes below vs other waves' OS reads (Y overlaps P[0])

  // ---------- proj epilogue: o + proj_b -> Y (bf16, over QK/VT/P[0] region) ----------
  #pragma unroll
  for (int nt = 0; nt < 4; ++nt) {
    int col = nq * 64 + nt * 16 + c16;
    float pb = proj_b[col];
    #pragma unroll
    for (int j = 0; j < 2; ++j)
      #pragma unroll
      for (int r = 0; r < 4; ++r) {
        int i = (2 * mh + j) * 16 + 4 * g + r;
        *(unsigned short*)(sm + L_Y + i * 512 + swzb(i, col * 2)) = f2bf(accP[nt][j][r] + pb);
      }
  }
  __syncthreads();

  // ---------- LN1 + residual: y = LN(o)*g+b + xw, in place on Y (bf16); 8 lanes/row ----------
  {
    int t = tid >> 3, oc = tid & 7;
    float v[32];
    float s1 = 0.f;
    #pragma unroll
    for (int b2 = 0; b2 < 4; ++b2) {
      s16x8 vb = *(const s16x8*)(sm + L_Y + t * 512 + swzb(t, oc * 64 + b2 * 16));
      #pragma unroll
      for (int e = 0; e < 8; ++e) { float fv = bf2f((unsigned short)vb[e]); v[b2*8+e] = fv; s1 += fv; }
    }
    s1 += __shfl_xor(s1, 1);
    s1 += __shfl_xor(s1, 2);
    s1 += __shfl_xor(s1, 4);
    float mu = s1 * (1.f / 256.f);
    float s2 = 0.f;
    #pragma unroll
    for (int e = 0; e < 32; ++e) { float d = v[e] - mu; s2 += d * d; }
    s2 += __shfl_xor(s2, 1);
    s2 += __shfl_xor(s2, 2);
    s2 += __shfl_xor(s2, 4);
    float rs = rsqrtf(s2 * (1.f / 256.f) + 1e-5f);
    #pragma unroll
    for (int b2 = 0; b2 < 4; ++b2) {
      s16x8 xb = *(const s16x8*)(sm + L_XW + t * 512 + swzb(t, oc * 64 + b2 * 16));
      s16x8 yb;
      #pragma unroll
      for (int e = 0; e < 8; ++e) {
        int c = oc * 32 + b2 * 8 + e;
        float yv = (v[b2*8+e] - mu) * rs * ln1w[c] + ln1b[c] + bf2f((unsigned short)xb[e]);
        yb[e] = (short)f2bf(yv);
      }
      *(s16x8*)(sm + L_Y + t * 512 + swzb(t, oc * 64 + b2 * 16)) = yb;
    }
  }
  __syncthreads();

  // ---------- MLP: fc1(gelu) in 4 chunks, fc2 accumulated in registers ----------
  f32x4 acc2[4][2];
  #pragma unroll
  for (int a = 0; a < 4; ++a)
    #pragma unroll
    for (int b = 0; b < 2; ++b) acc2[a][b] = f32x4{0.f,0.f,0.f,0.f};

  #pragma unroll 1
  for (int cc = 0; cc < 4; ++cc) {
    f32x4 acc1[4][2];
    #pragma unroll
    for (int a = 0; a < 4; ++a)
      #pragma unroll
      for (int b = 0; b < 2; ++b) acc1[a][b] = f32x4{0.f,0.f,0.f,0.f};
    for (int k0 = 0; k0 < 256; k0 += 32) {
      s16x8 af[2];
      #pragma unroll
      for (int j = 0; j < 2; ++j) {
        int row = (2 * mh + j) * 16 + c16;
        af[j] = *(const s16x8*)(sm + L_Y + row * 512 + swzb(row, (k0 + g * 8) * 2));
      }
      #pragma unroll
      for (int nt = 0; nt < 4; ++nt) {
        int gt = cc * 16 + nq * 4 + nt;
        s16x8 bfr = *(const s16x8*)(fc1w + ((gt * 32 + (k0 >> 3) + g) * 16 + c16) * 8);
        #pragma unroll
        for (int j = 0; j < 2; ++j)
          acc1[nt][j] = __builtin_amdgcn_mfma_f32_16x16x32_bf16(af[j], bfr, acc1[nt][j], 0, 0, 0);
      }
    }
    // gelu (tanh form) + store H chunk (aliases XW; dead after LN1)
    #pragma unroll
    for (int nt = 0; nt < 4; ++nt) {
      int coll = nq * 64 + nt * 16 + c16;
      float b1v = fc1b[cc * 256 + coll];
      #pragma unroll
      for (int j = 0; j < 2; ++j)
        #pragma unroll
        for (int r = 0; r < 4; ++r) {
          int i = (2 * mh + j) * 16 + 4 * g + r;
          float u = acc1[nt][j][r] + b1v;
          float z = 0.7978845608f * u * (1.f + 0.044715f * u * u);
          float e2 = __expf(2.f * z);
          float ge = u * e2 / (e2 + 1.f);
          *(unsigned short*)(sm + L_H + i * 512 + swzb(i, coll * 2)) = f2bf(ge);
        }
    }
    __syncthreads();
    // fc2 partial: acc2 += H_chunk @ fc2[cc*256.., :]
    for (int k0 = 0; k0 < 256; k0 += 32) {
      s16x8 af[2];
      #pragma unroll
      for (int j = 0; j < 2; ++j) {
        int row = (2 * mh + j) * 16 + c16;
        af[j] = *(const s16x8*)(sm + L_H + row * 512 + swzb(row, (k0 + g * 8) * 2));
      }
      #pragma unroll
      for (int nt = 0; nt < 4; ++nt) {
        int kg = cc * 32 + (k0 >> 3) + g;
        s16x8 bfr = *(const s16x8*)(fc2w + (((nq * 4 + nt) * 128 + kg) * 16 + c16) * 8);
        #pragma unroll
        for (int j = 0; j < 2; ++j)
          acc2[nt][j] = __builtin_amdgcn_mfma_f32_16x16x32_bf16(af[j], bfr, acc2[nt][j], 0, 0, 0);
      }
    }
    __syncthreads();
  }

  // ---------- fc2 epilogue -> MB bf16 (aliases H) ----------
  #pragma unroll
  for (int nt = 0; nt < 4; ++nt) {
    int col = nq * 64 + nt * 16 + c16;
    float b2v = fc2b[col];
    #pragma unroll
    for (int j = 0; j < 2; ++j)
      #pragma unroll
      for (int r = 0; r < 4; ++r) {
        int i = (2 * mh + j) * 16 + 4 * g + r;
        *(unsigned short*)(sm + L_MB + i * 512 + swzb(i, col * 2)) = f2bf(acc2[nt][j][r] + b2v);
      }
  }
  __syncthreads();

  // ---------- LN2 + residual; direct bf16 store to sout (64B/thread contiguous) ----------
  {
    int t2 = tid >> 3, oc = tid & 7;
    float v[32];
    float s1 = 0.f;
    #pragma unroll
    for (int b2 = 0; b2 < 4; ++b2) {
      s16x8 vb = *(const s16x8*)(sm + L_MB + t2 * 512 + swzb(t2, oc * 64 + b2 * 16));
      #pragma unroll
      for (int e = 0; e < 8; ++e) { float fv = bf2f((unsigned short)vb[e]); v[b2*8+e] = fv; s1 += fv; }
    }
    s1 += __shfl_xor(s1, 1);
    s1 += __shfl_xor(s1, 2);
    s1 += __shfl_xor(s1, 4);
    float mu = s1 * (1.f / 256.f);
    float s2 = 0.f;
    #pragma unroll
    for (int e = 0; e < 32; ++e) { float d = v[e] - mu; s2 += d * d; }
    s2 += __shfl_xor(s2, 1);
    s2 += __shfl_xor(s2, 2);
    s2 += __shfl_xor(s2, 4);
    float rs = rsqrtf(s2 * (1.f / 256.f) + 1e-5f);
    int rp = (wi * 8 + (t2 >> 3) + 4) & 255;
    int cp = (wj * 8 + (t2 & 7) + 4) & 255;
    size_t pix = (size_t)bb * 65536 + rp * 256 + cp;
    unsigned short* so = sout + pix * 256 + oc * 32;
    #pragma unroll
    for (int b2 = 0; b2 < 4; ++b2) {
      s16x8 yb = *(const s16x8*)(sm + L_Y + t2 * 512 + swzb(t2, oc * 64 + b2 * 16));
      s16x8 pk;
      #pragma unroll
      for (int e = 0; e < 8; ++e) {
        int c = oc * 32 + b2 * 8 + e;
        float yv = (v[b2*8+e] - mu) * rs * ln2w[c] + ln2b[c] + bf2f((unsigned short)yb[e]);
        pk[e] = (short)f2bf(yv);
      }
      *(s16x8*)(so + b2 * 8) = pk;
    }
  }
}

extern "C" void kernel_launch(void* const* d_in, const int* in_sizes, int n_in,
                              void* d_out, int out_size, void* d_ws, size_t ws_size,
                              hipStream_t stream) {
  const float* x      = (const float*)d_in[0];
  const float* qkv_w  = (const float*)d_in[1];
  const float* ls     = (const float*)d_in[2];
  const float* proj_w = (const float*)d_in[3];
  const float* proj_b = (const float*)d_in[4];
  const float* ln1w   = (const float*)d_in[5];
  const float* ln1b   = (const float*)d_in[6];
  const float* fc1_w  = (const float*)d_in[7];
  const float* fc1b   = (const float*)d_in[8];
  const float* fc2_w  = (const float*)d_in[9];
  const float* fc2b   = (const float*)d_in[10];
  const float* ln2w   = (const float*)d_in[11];
  const float* ln2b   = (const float*)d_in[12];
  const float* cpb_w1 = (const float*)d_in[13];
  const float* cpb_b1 = (const float*)d_in[14];
  const float* cpb_w2 = (const float*)d_in[15];
  unsigned char* wsb = (unsigned char*)d_ws;
  float* out = (float*)d_out;

  hipFuncSetAttribute(reinterpret_cast<const void*>(swin_block_kernel),
                      hipFuncAttributeMaxDynamicSharedMemorySize, SMEM_BYTES);

  prep_pack_kernel<<<3072, 256, 0, stream>>>(qkv_w, proj_w, fc1_w, fc2_w, wsb);
  prep_bias_kernel<<<1, 256, 0, stream>>>(cpb_w1, cpb_b1, cpb_w2, wsb);
  transpose_in_kernel<<<8192, 256, 0, stream>>>(x, wsb);
  swin_block_kernel<<<2048, 512, SMEM_BYTES, stream>>>(
      ls, proj_b, ln1w, ln1b, fc1b, fc2b, ln2w, ln2b, wsb);
  transpose_out_kernel<<<8192, 256, 0, stream>>>(wsb, out);
}

// Round 7
// 619.093 us; speedup vs baseline: 3.4095x; 3.4095x over previous
//
#include <hip/hip_runtime.h>
#include <hip/hip_bf16.h>

typedef __attribute__((ext_vector_type(4))) float f32x4;
typedef __attribute__((ext_vector_type(8))) short s16x8;
typedef __attribute__((ext_vector_type(4))) unsigned short u16x4;

// ---- LDS layout (byte offsets), total 135168 B (1 block/CU by design) ----
#define L_XW   0        // bf16 [64][256] swzb rows 512B; later H (fc1 chunk), then MB
#define L_QKV  32768    // per head h at 32768+h*12288: q[64][64B] | k[64][64B] | vt[32][128B]
                        //   P[64][128B] overwrites q|k ; O[64][64B] overwrites P rows 0..31
#define L_Y    32768    // bf16 [64][512B] swzb (aliases heads 0..2 region after proj)
#define L_NQ   131072   // f32 [8][64]: scale/|q_i|
#define L_NK   133120   // f32 [8][64]: 1/|k_j|
#define SMEM_BYTES 135168

// ---- workspace layout (byte offsets) ----
#define WSO_BIAS   0          // f32 [8][64][16][4] packed (h,i,c16,nt)   131072 B
#define WSO_QKVW   131072     // bf16 [48][32][16][8]       393216 B
#define WSO_PROJW  524288     // bf16 [16][32][16][8]       131072 B
#define WSO_FC1W   655360     // bf16 [64][32][16][8]       524288 B
#define WSO_FC2W   1179648    // bf16 [16][128][16][8]      524288 B
#define WSO_SIN    1703936ULL // bf16 [2][65536][256]       67108864 B
#define WSO_SOUT   68812800ULL// bf16 [2][65536][256]       67108864 B

__device__ __forceinline__ unsigned short f2bf(float f) {
  __hip_bfloat16 h = __float2bfloat16(f);   // RNE; compiler pairs into v_cvt_pk_bf16_f32
  return __builtin_bit_cast(unsigned short, h);
}
__device__ __forceinline__ float bf2f(unsigned short b) {
  union { unsigned u; float f; } v; v.u = ((unsigned)b) << 16;
  return v.f;
}
__device__ __forceinline__ int swzb(int row, int byteoff) {  // 128B+ rows
  return byteoff ^ ((row & 7) << 4);
}
__device__ __forceinline__ int swz64(int row, int byteoff) { // 64B rows
  return byteoff ^ ((row & 3) << 4);
}

// ---------------- prep: pack all weights to bf16 MFMA-fragment layout ----------------
__global__ void prep_pack_kernel(const float* __restrict__ qkv_w,
                                 const float* __restrict__ proj_w,
                                 const float* __restrict__ fc1_w,
                                 const float* __restrict__ fc2_w,
                                 unsigned char* __restrict__ wsb) {
  int e = blockIdx.x * 256 + threadIdx.x;   // 0 .. 786431
  const float* src; unsigned short* dst; int K, N; int eo;
  if (e < 196608)       { eo = e;          src = qkv_w;  dst = (unsigned short*)(wsb + WSO_QKVW);  K = 256;  N = 768; }
  else if (e < 262144)  { eo = e - 196608; src = proj_w; dst = (unsigned short*)(wsb + WSO_PROJW); K = 256;  N = 256; }
  else if (e < 524288)  { eo = e - 262144; src = fc1_w;  dst = (unsigned short*)(wsb + WSO_FC1W);  K = 256;  N = 1024; }
  else                  { eo = e - 524288; src = fc2_w;  dst = (unsigned short*)(wsb + WSO_FC2W);  K = 1024; N = 256; }
  int j = eo & 7, c = (eo >> 3) & 15, rest = eo >> 7;
  int Kg = K >> 3;
  int kg = rest % Kg, nt = rest / Kg;
  dst[eo] = f2bf(src[(kg * 8 + j) * N + nt * 16 + c]);
}

// ---------------- prep: relative-position-bias table via CPB MLP (packed float4) ----------------
__global__ void prep_bias_kernel(const float* __restrict__ cpb_w1,
                                 const float* __restrict__ cpb_b1,
                                 const float* __restrict__ cpb_w2,
                                 unsigned char* __restrict__ wsb) {
  __shared__ float bt[225][8];
  int tid = threadIdx.x;
  for (int t = tid; t < 225; t += 256) {
    int a = t / 15, b = t % 15;
    float r0 = (float)(a - 7) * (8.0f / 7.0f);
    float r1 = (float)(b - 7) * (8.0f / 7.0f);
    float f0 = (r0 >= 0.f ? 1.f : -1.f) * log2f(fabsf(r0) + 1.f) * (1.f / 3.f);
    float f1 = (r1 >= 0.f ? 1.f : -1.f) * log2f(fabsf(r1) + 1.f) * (1.f / 3.f);
    float acc[8] = {0.f,0.f,0.f,0.f,0.f,0.f,0.f,0.f};
    for (int k = 0; k < 512; ++k) {
      float hv = f0 * cpb_w1[k] + f1 * cpb_w1[512 + k] + cpb_b1[k];
      hv = fmaxf(hv, 0.f);
      #pragma unroll
      for (int h = 0; h < 8; ++h) acc[h] += hv * cpb_w2[k * 8 + h];
    }
    #pragma unroll
    for (int h = 0; h < 8; ++h) bt[t][h] = acc[h];
  }
  __syncthreads();
  float* biasp = (float*)(wsb + WSO_BIAS);
  for (int e = tid; e < 32768; e += 256) {
    int nn = e & 3, cc = (e >> 2) & 15, i = (e >> 6) & 63, h = e >> 12;
    int j = nn * 16 + cc;
    int dr = (i >> 3) - (j >> 3) + 7, dc = (i & 7) - (j & 7) + 7;
    float v = bt[dr * 15 + dc][h];
    biasp[e] = 16.f / (1.f + expf(-v));
  }
}

// ---------------- pass A: x[b][c][p] f32 -> sin[b][p][c] bf16 (tiled transpose) ----------------
__global__ __launch_bounds__(256)
void transpose_in_kernel(const float* __restrict__ x, unsigned char* __restrict__ wsb) {
  __shared__ float tile[64][65];
  int pb = blockIdx.x & 1023;
  int cg = (blockIdx.x >> 10) & 3;
  int b  = blockIdx.x >> 12;
  int p0 = pb * 64, c0 = cg * 64;
  int tid = threadIdx.x;
  unsigned short* sg = (unsigned short*)(wsb + WSO_SIN);

  int pi = tid & 63, cq = tid >> 6;
  for (int r = 0; r < 16; ++r) {
    int c = cq * 16 + r;
    tile[pi][c] = x[((size_t)(b * 256 + c0 + c)) * 65536 + p0 + pi];
  }
  __syncthreads();
  int po = tid >> 2, co = tid & 3;
  s16x8 pk0, pk1;
  #pragma unroll
  for (int j = 0; j < 8; ++j) {
    pk0[j] = (short)f2bf(tile[po][co * 16 + j]);
    pk1[j] = (short)f2bf(tile[po][co * 16 + 8 + j]);
  }
  unsigned short* dp = sg + ((size_t)b * 65536 + p0 + po) * 256 + c0 + co * 16;
  *(s16x8*)(dp) = pk0;
  *(s16x8*)(dp + 8) = pk1;
}

// ---------------- pass B: sout[b][p][c] bf16 -> out[b][c][p] f32 (tiled transpose) ----------------
__global__ __launch_bounds__(256)
void transpose_out_kernel(const unsigned char* __restrict__ wsb, float* __restrict__ out) {
  __shared__ float tile[64][65];
  int pb = blockIdx.x & 1023;
  int cg = (blockIdx.x >> 10) & 3;
  int b  = blockIdx.x >> 12;
  int p0 = pb * 64, c0 = cg * 64;
  int tid = threadIdx.x;
  const unsigned short* sg = (const unsigned short*)(wsb + WSO_SOUT);

  int pi = tid >> 2, cq = tid & 3;
  const unsigned short* rp = sg + ((size_t)b * 65536 + p0 + pi) * 256 + c0 + cq * 16;
  s16x8 a0 = *(const s16x8*)(rp);
  s16x8 a1 = *(const s16x8*)(rp + 8);
  #pragma unroll
  for (int j = 0; j < 8; ++j) {
    tile[pi][cq * 16 + j]     = bf2f((unsigned short)a0[j]);
    tile[pi][cq * 16 + 8 + j] = bf2f((unsigned short)a1[j]);
  }
  __syncthreads();
  int ci = tid >> 6, pi2 = tid & 63;
  for (int r = 0; r < 16; ++r) {
    int c = ci * 16 + r;
    out[((size_t)(b * 256 + c0 + c)) * 65536 + p0 + pi2] = tile[pi2][c];
  }
}

// ---------------- main fused per-window kernel: 512 threads / 8 waves, wave=head ----------------
// Occupancy ceiling is 2 waves/SIMD (arch-VGPR file ~256/lane; rounds 4-6 evidence), so LDS is
// spent freely (135 KiB, 1 block/CU). The whole qkv->attention stretch is wave-private: no barriers.
__global__ __launch_bounds__(512, 2)
void swin_block_kernel(const float* __restrict__ ls,
                       const float* __restrict__ proj_b,
                       const float* __restrict__ ln1w, const float* __restrict__ ln1b,
                       const float* __restrict__ fc1b,
                       const float* __restrict__ fc2b,
                       const float* __restrict__ ln2w, const float* __restrict__ ln2b,
                       unsigned char* __restrict__ wsb) {
  extern __shared__ char sm[];
  const int tid = threadIdx.x;
  const int w = tid >> 6;       // wave id = head id in attention
  const int lane = tid & 63;
  const int g = lane >> 4;
  const int c16 = lane & 15;

  const int blk = blockIdx.x;
  const int bb = blk >> 10;
  const int widx = blk & 1023;
  const int wi = widx >> 5, wj = widx & 31;

  const f32x4* biasv = (const f32x4*)(wsb + WSO_BIAS);
  const unsigned short* qkvw = (const unsigned short*)(wsb + WSO_QKVW);
  const unsigned short* projw = (const unsigned short*)(wsb + WSO_PROJW);
  const unsigned short* fc1w = (const unsigned short*)(wsb + WSO_FC1W);
  const unsigned short* fc2w = (const unsigned short*)(wsb + WSO_FC2W);
  const unsigned short* sin_ = (const unsigned short*)(wsb + WSO_SIN);
  unsigned short* sout = (unsigned short*)(wsb + WSO_SOUT);

  // ---------- Phase 1: copy window from sin (channel-contiguous) -> XW bf16 swz ----------
  #pragma unroll
  for (int it = 0; it < 4; ++it) {
    int u = tid + it * 512;              // 16B units: u = t*32 + cu
    int t = u >> 5, cu = u & 31;
    int rp = (wi * 8 + (t >> 3) + 4) & 255;
    int cp = (wj * 8 + (t & 7) + 4) & 255;
    size_t pix = (size_t)bb * 65536 + rp * 256 + cp;
    s16x8 v = *(const s16x8*)(sin_ + pix * 256 + cu * 8);
    *(s16x8*)(sm + L_XW + t * 512 + swzb(t, cu * 16)) = v;
  }
  __syncthreads();   // B1

  char* const QB = sm + L_QKV + w * 12288;   // this wave's head slab

  // ---------- Phase Q: qkv GEMM, wave w computes head w (q0,q1,k0,k1,v0,v1 tiles) ----------
  {
    int tiles[6] = {2*w, 2*w+1, 16+2*w, 17+2*w, 32+2*w, 33+2*w};
    f32x4 acc[6][4];
    #pragma unroll
    for (int a = 0; a < 6; ++a)
      #pragma unroll
      for (int b = 0; b < 4; ++b) acc[a][b] = f32x4{0.f,0.f,0.f,0.f};
    #pragma unroll 2
    for (int k0 = 0; k0 < 256; k0 += 32) {
      s16x8 af[4];
      #pragma unroll
      for (int mt = 0; mt < 4; ++mt) {
        int row = mt * 16 + c16;
        af[mt] = *(const s16x8*)(sm + L_XW + row * 512 + swzb(row, (k0 + g * 8) * 2));
      }
      #pragma unroll
      for (int ct = 0; ct < 6; ++ct) {
        s16x8 bfr = *(const s16x8*)(qkvw + ((tiles[ct] * 32 + (k0 >> 3) + g) * 16 + c16) * 8);
        #pragma unroll
        for (int mt = 0; mt < 4; ++mt)
          acc[ct][mt] = __builtin_amdgcn_mfma_f32_16x16x32_bf16(af[mt], bfr, acc[ct][mt], 0, 0, 0);
      }
    }
    // epilogue: store q,k raw bf16; v transposed+permuted; compute norms from f32 acc
    float lsc = __expf(fminf(ls[w], 4.6051702f));
    float* nqp = (float*)(sm + L_NQ) + w * 64;
    float* nkp = (float*)(sm + L_NK) + w * 64;
    #pragma unroll
    for (int mt = 0; mt < 4; ++mt)
      #pragma unroll
      for (int r = 0; r < 4; ++r) {
        int i = mt * 16 + 4 * g + r;
        float sq = 0.f, sk = 0.f;
        #pragma unroll
        for (int dt = 0; dt < 2; ++dt) {
          float vq = acc[dt][mt][r];     sq += vq * vq;
          float vk = acc[2 + dt][mt][r]; sk += vk * vk;
          float vv = acc[4 + dt][mt][r];
          *(unsigned short*)(QB + i * 64 + swz64(i, (dt * 16 + c16) * 2)) = f2bf(vq);
          *(unsigned short*)(QB + 4096 + i * 64 + swz64(i, (dt * 16 + c16) * 2)) = f2bf(vk);
          int d = dt * 16 + c16;
          int jp = 4 * (i & 15) + (i >> 4);     // permuted token index
          *(unsigned short*)(QB + 8192 + d * 128 + swzb(d, jp * 2)) = f2bf(vv);
        }
        sq += __shfl_xor(sq, 1); sq += __shfl_xor(sq, 2);
        sq += __shfl_xor(sq, 4); sq += __shfl_xor(sq, 8);
        sk += __shfl_xor(sk, 1); sk += __shfl_xor(sk, 2);
        sk += __shfl_xor(sk, 4); sk += __shfl_xor(sk, 8);
        if (c16 == 0) {
          nqp[i] = lsc / fmaxf(sqrtf(sq), 1e-12f);
          nkp[i] = 1.f / fmaxf(sqrtf(sk), 1e-12f);
        }
      }
  }
  // NO barrier: everything below (S, softmax, PV, O) touches only wave-private data.

  // ---------- Phase A: S = q k^T, softmax(+bias+mask+norms), PV -> O ----------
  {
    // S: 16 MFMAs (4 m-tiles x 4 n-tiles), K=32
    s16x8 qf[4];
    #pragma unroll
    for (int mt = 0; mt < 4; ++mt) {
      int row = mt * 16 + c16;
      qf[mt] = *(const s16x8*)(QB + row * 64 + swz64(row, g * 16));
    }
    f32x4 S[4][4];
    #pragma unroll
    for (int nt = 0; nt < 4; ++nt) {
      int row = nt * 16 + c16;
      s16x8 kf = *(const s16x8*)(QB + 4096 + row * 64 + swz64(row, g * 16));
      #pragma unroll
      for (int mt = 0; mt < 4; ++mt)
        S[mt][nt] = __builtin_amdgcn_mfma_f32_16x16x32_bf16(qf[mt], kf, f32x4{0.f,0.f,0.f,0.f}, 0, 0, 0);
    }
    // softmax per row (16 rows/thread), norms folded in, P stored j-permuted (b64 packed)
    const float* nqp = (const float*)(sm + L_NQ) + w * 64;
    const float* nkp = (const float*)(sm + L_NK) + w * 64;
    float rk4[4];
    int labj[4];
    #pragma unroll
    for (int nt = 0; nt < 4; ++nt) {
      int jj = nt * 16 + c16;
      rk4[nt] = nkp[jj];
      int tr = jj >> 3, tc = jj & 7;
      labj[nt] = ((wi == 31) ? (tr >= 4 ? 2 : 1) : 0) * 3 + ((wj == 31) ? (tc >= 4 ? 2 : 1) : 0);
    }
    #pragma unroll
    for (int mt = 0; mt < 4; ++mt)
      #pragma unroll
      for (int r = 0; r < 4; ++r) {
        int i = mt * 16 + 4 * g + r;
        float rq = nqp[i];
        f32x4 bb4 = biasv[(w * 64 + i) * 16 + c16];
        int tr = i >> 3, tc = i & 7;
        int labi = ((wi == 31) ? (tr >= 4 ? 2 : 1) : 0) * 3 + ((wj == 31) ? (tc >= 4 ? 2 : 1) : 0);
        float vv[4];
        float mx = -1e30f;
        #pragma unroll
        for (int nt = 0; nt < 4; ++nt) {
          float v = S[mt][nt][r] * rq * rk4[nt] + bb4[nt];
          if (labi != labj[nt]) v -= 100.f;
          vv[nt] = v;
          mx = fmaxf(mx, v);
        }
        mx = fmaxf(mx, __shfl_xor(mx, 1));
        mx = fmaxf(mx, __shfl_xor(mx, 2));
        mx = fmaxf(mx, __shfl_xor(mx, 4));
        mx = fmaxf(mx, __shfl_xor(mx, 8));
        float sum = 0.f;
        #pragma unroll
        for (int nt = 0; nt < 4; ++nt) { vv[nt] = __expf(vv[nt] - mx); sum += vv[nt]; }
        sum += __shfl_xor(sum, 1);
        sum += __shfl_xor(sum, 2);
        sum += __shfl_xor(sum, 4);
        sum += __shfl_xor(sum, 8);
        float inv = 1.f / sum;
        u16x4 pk;
        #pragma unroll
        for (int nt = 0; nt < 4; ++nt) pk[nt] = f2bf(vv[nt] * inv);   // col' = 4*c16+nt
        *(u16x4*)(QB + i * 128 + swzb(i, c16 * 8)) = pk;
      }
    // PV: O = P @ V (j-permuted on both operands), 16 MFMAs
    f32x4 O[4][2];
    #pragma unroll
    for (int a = 0; a < 4; ++a)
      #pragma unroll
      for (int b = 0; b < 2; ++b) O[a][b] = f32x4{0.f,0.f,0.f,0.f};
    #pragma unroll
    for (int k0 = 0; k0 < 64; k0 += 32) {
      s16x8 pf[4];
      #pragma unroll
      for (int mt = 0; mt < 4; ++mt) {
        int row = mt * 16 + c16;
        pf[mt] = *(const s16x8*)(QB + row * 128 + swzb(row, (k0 + g * 8) * 2));
      }
      #pragma unroll
      for (int nt = 0; nt < 2; ++nt) {
        int d = nt * 16 + c16;
        s16x8 vf = *(const s16x8*)(QB + 8192 + d * 128 + swzb(d, (k0 + g * 8) * 2));
        #pragma unroll
        for (int mt = 0; mt < 4; ++mt)
          O[mt][nt] = __builtin_amdgcn_mfma_f32_16x16x32_bf16(pf[mt], vf, O[mt][nt], 0, 0, 0);
      }
    }
    // O store (own slab; all P reads above are same-wave, DS in-order)
    #pragma unroll
    for (int mt = 0; mt < 4; ++mt)
      #pragma unroll
      for (int nt = 0; nt < 2; ++nt)
        #pragma unroll
        for (int r = 0; r < 4; ++r) {
          int i = mt * 16 + 4 * g + r;
          int d = nt * 16 + c16;
          *(unsigned short*)(QB + i * 64 + swz64(i, d * 2)) = f2bf(O[mt][nt][r]);
        }
  }
  __syncthreads();   // B2: all heads' O complete

  // ---------- Phase P: proj (K = 8 heads x 32), wave w -> col-tiles 2w, 2w+1 ----------
  {
    f32x4 aP[2][4];
    #pragma unroll
    for (int a = 0; a < 2; ++a)
      #pragma unroll
      for (int b = 0; b < 4; ++b) aP[a][b] = f32x4{0.f,0.f,0.f,0.f};
    #pragma unroll 2
    for (int k0 = 0; k0 < 256; k0 += 32) {
      int hk = k0 >> 5;
      const char* OBk = sm + L_QKV + hk * 12288;
      s16x8 af[4];
      #pragma unroll
      for (int mt = 0; mt < 4; ++mt) {
        int row = mt * 16 + c16;
        af[mt] = *(const s16x8*)(OBk + row * 64 + swz64(row, g * 16));
      }
      #pragma unroll
      for (int t2 = 0; t2 < 2; ++t2) {
        s16x8 bfr = *(const s16x8*)(projw + (((2*w + t2) * 32 + 4*hk + g) * 16 + c16) * 8);
        #pragma unroll
        for (int mt = 0; mt < 4; ++mt)
          aP[t2][mt] = __builtin_amdgcn_mfma_f32_16x16x32_bf16(af[mt], bfr, aP[t2][mt], 0, 0, 0);
      }
    }
    __syncthreads();   // B3: O reads done before Y (aliased region) writes
    #pragma unroll
    for (int t2 = 0; t2 < 2; ++t2) {
      int col = (2*w + t2) * 16 + c16;
      float pb = proj_b[col];
      #pragma unroll
      for (int mt = 0; mt < 4; ++mt)
        #pragma unroll
        for (int r = 0; r < 4; ++r) {
          int i = mt * 16 + 4 * g + r;
          *(unsigned short*)(sm + L_Y + i * 512 + swzb(i, col * 2)) = f2bf(aP[t2][mt][r] + pb);
        }
    }
  }
  __syncthreads();   // B4

  // ---------- LN1 + residual: y = LN(o)*g+b + xw, in place on Y; 8 lanes/row ----------
  {
    int t = tid >> 3, oc = tid & 7;
    float v[32];
    float s1 = 0.f;
    #pragma unroll
    for (int b2 = 0; b2 < 4; ++b2) {
      s16x8 vb = *(const s16x8*)(sm + L_Y + t * 512 + swzb(t, oc * 64 + b2 * 16));
      #pragma unroll
      for (int e = 0; e < 8; ++e) { float fv = bf2f((unsigned short)vb[e]); v[b2*8+e] = fv; s1 += fv; }
    }
    s1 += __shfl_xor(s1, 1);
    s1 += __shfl_xor(s1, 2);
    s1 += __shfl_xor(s1, 4);
    float mu = s1 * (1.f / 256.f);
    float s2 = 0.f;
    #pragma unroll
    for (int e = 0; e < 32; ++e) { float d = v[e] - mu; s2 += d * d; }
    s2 += __shfl_xor(s2, 1);
    s2 += __shfl_xor(s2, 2);
    s2 += __shfl_xor(s2, 4);
    float rs = rsqrtf(s2 * (1.f / 256.f) + 1e-5f);
    #pragma unroll
    for (int b2 = 0; b2 < 4; ++b2) {
      s16x8 xb = *(const s16x8*)(sm + L_XW + t * 512 + swzb(t, oc * 64 + b2 * 16));
      s16x8 yb;
      #pragma unroll
      for (int e = 0; e < 8; ++e) {
        int c = oc * 32 + b2 * 8 + e;
        float yv = (v[b2*8+e] - mu) * rs * ln1w[c] + ln1b[c] + bf2f((unsigned short)xb[e]);
        yb[e] = (short)f2bf(yv);
      }
      *(s16x8*)(sm + L_Y + t * 512 + swzb(t, oc * 64 + b2 * 16)) = yb;
    }
  }
  __syncthreads();   // B5 (also orders XW reads before H overwrites XW)

  // ---------- MLP: fc1(gelu) in 4 chunks -> H (XW region), fc2 accumulated in registers ----------
  f32x4 acc2[2][4];
  #pragma unroll
  for (int a = 0; a < 2; ++a)
    #pragma unroll
    for (int b = 0; b < 4; ++b) acc2[a][b] = f32x4{0.f,0.f,0.f,0.f};

  #pragma unroll 1
  for (int cc = 0; cc < 4; ++cc) {
    f32x4 acc1[2][4];
    #pragma unroll
    for (int a = 0; a < 2; ++a)
      #pragma unroll
      for (int b = 0; b < 4; ++b) acc1[a][b] = f32x4{0.f,0.f,0.f,0.f};
    for (int k0 = 0; k0 < 256; k0 += 32) {
      s16x8 af[4];
      #pragma unroll
      for (int mt = 0; mt < 4; ++mt) {
        int row = mt * 16 + c16;
        af[mt] = *(const s16x8*)(sm + L_Y + row * 512 + swzb(row, (k0 + g * 8) * 2));
      }
      #pragma unroll
      for (int t2 = 0; t2 < 2; ++t2) {
        int gt = cc * 16 + 2*w + t2;
        s16x8 bfr = *(const s16x8*)(fc1w + ((gt * 32 + (k0 >> 3) + g) * 16 + c16) * 8);
        #pragma unroll
        for (int mt = 0; mt < 4; ++mt)
          acc1[t2][mt] = __builtin_amdgcn_mfma_f32_16x16x32_bf16(af[mt], bfr, acc1[t2][mt], 0, 0, 0);
      }
    }
    // gelu (tanh form) + store H chunk
    #pragma unroll
    for (int t2 = 0; t2 < 2; ++t2) {
      int coll = (2*w + t2) * 16 + c16;
      float b1v = fc1b[cc * 256 + coll];
      #pragma unroll
      for (int mt = 0; mt < 4; ++mt)
        #pragma unroll
        for (int r = 0; r < 4; ++r) {
          int i = mt * 16 + 4 * g + r;
          float u = acc1[t2][mt][r] + b1v;
          float z = 0.7978845608f * u * (1.f + 0.044715f * u * u);
          float e2 = __expf(2.f * z);
          float ge = u * e2 / (e2 + 1.f);
          *(unsigned short*)(sm + L_XW + i * 512 + swzb(i, coll * 2)) = f2bf(ge);
        }
    }
    __syncthreads();
    // fc2 partial: acc2 += H_chunk @ fc2[cc*256.., :]
    for (int k0 = 0; k0 < 256; k0 += 32) {
      s16x8 af[4];
      #pragma unroll
      for (int mt = 0; mt < 4; ++mt) {
        int row = mt * 16 + c16;
        af[mt] = *(const s16x8*)(sm + L_XW + row * 512 + swzb(row, (k0 + g * 8) * 2));
      }
      #pragma unroll
      for (int t2 = 0; t2 < 2; ++t2) {
        int kg = cc * 32 + (k0 >> 3) + g;
        s16x8 bfr = *(const s16x8*)(fc2w + (((2*w + t2) * 128 + kg) * 16 + c16) * 8);
        #pragma unroll
        for (int mt = 0; mt < 4; ++mt)
          acc2[t2][mt] = __builtin_amdgcn_mfma_f32_16x16x32_bf16(af[mt], bfr, acc2[t2][mt], 0, 0, 0);
      }
    }
    __syncthreads();
  }

  // ---------- fc2 epilogue -> MB (XW region, H dead) ----------
  #pragma unroll
  for (int t2 = 0; t2 < 2; ++t2) {
    int col = (2*w + t2) * 16 + c16;
    float b2v = fc2b[col];
    #pragma unroll
    for (int mt = 0; mt < 4; ++mt)
      #pragma unroll
      for (int r = 0; r < 4; ++r) {
        int i = mt * 16 + 4 * g + r;
        *(unsigned short*)(sm + L_XW + i * 512 + swzb(i, col * 2)) = f2bf(acc2[t2][mt][r] + b2v);
      }
  }
  __syncthreads();   // B6

  // ---------- LN2 + residual; direct bf16 store to sout (64B/thread contiguous) ----------
  {
    int t2 = tid >> 3, oc = tid & 7;
    float v[32];
    float s1 = 0.f;
    #pragma unroll
    for (int b2 = 0; b2 < 4; ++b2) {
      s16x8 vb = *(const s16x8*)(sm + L_XW + t2 * 512 + swzb(t2, oc * 64 + b2 * 16));
      #pragma unroll
      for (int e = 0; e < 8; ++e) { float fv = bf2f((unsigned short)vb[e]); v[b2*8+e] = fv; s1 += fv; }
    }
    s1 += __shfl_xor(s1, 1);
    s1 += __shfl_xor(s1, 2);
    s1 += __shfl_xor(s1, 4);
    float mu = s1 * (1.f / 256.f);
    float s2 = 0.f;
    #pragma unroll
    for (int e = 0; e < 32; ++e) { float d = v[e] - mu; s2 += d * d; }
    s2 += __shfl_xor(s2, 1);
    s2 += __shfl_xor(s2, 2);
    s2 += __shfl_xor(s2, 4);
    float rs = rsqrtf(s2 * (1.f / 256.f) + 1e-5f);
    int rp = (wi * 8 + (t2 >> 3) + 4) & 255;
    int cp = (wj * 8 + (t2 & 7) + 4) & 255;
    size_t pix = (size_t)bb * 65536 + rp * 256 + cp;
    unsigned short* so = sout + pix * 256 + oc * 32;
    #pragma unroll
    for (int b2 = 0; b2 < 4; ++b2) {
      s16x8 yb = *(const s16x8*)(sm + L_Y + t2 * 512 + swzb(t2, oc * 64 + b2 * 16));
      s16x8 pk;
      #pragma unroll
      for (int e = 0; e < 8; ++e) {
        int c = oc * 32 + b2 * 8 + e;
        float yv = (v[b2*8+e] - mu) * rs * ln2w[c] + ln2b[c] + bf2f((unsigned short)yb[e]);
        pk[e] = (short)f2bf(yv);
      }
      *(s16x8*)(so + b2 * 8) = pk;
    }
  }
}

extern "C" void kernel_launch(void* const* d_in, const int* in_sizes, int n_in,
                              void* d_out, int out_size, void* d_ws, size_t ws_size,
                              hipStream_t stream) {
  const float* x      = (const float*)d_in[0];
  const float* qkv_w  = (const float*)d_in[1];
  const float* ls     = (const float*)d_in[2];
  const float* proj_w = (const float*)d_in[3];
  const float* proj_b = (const float*)d_in[4];
  const float* ln1w   = (const float*)d_in[5];
  const float* ln1b   = (const float*)d_in[6];
  const float* fc1_w  = (const float*)d_in[7];
  const float* fc1b   = (const float*)d_in[8];
  const float* fc2_w  = (const float*)d_in[9];
  const float* fc2b   = (const float*)d_in[10];
  const float* ln2w   = (const float*)d_in[11];
  const float* ln2b   = (const float*)d_in[12];
  const float* cpb_w1 = (const float*)d_in[13];
  const float* cpb_b1 = (const float*)d_in[14];
  const float* cpb_w2 = (const float*)d_in[15];
  unsigned char* wsb = (unsigned char*)d_ws;
  float* out = (float*)d_out;

  hipFuncSetAttribute(reinterpret_cast<const void*>(swin_block_kernel),
                      hipFuncAttributeMaxDynamicSharedMemorySize, SMEM_BYTES);

  prep_pack_kernel<<<3072, 256, 0, stream>>>(qkv_w, proj_w, fc1_w, fc2_w, wsb);
  prep_bias_kernel<<<1, 256, 0, stream>>>(cpb_w1, cpb_b1, cpb_w2, wsb);
  transpose_in_kernel<<<8192, 256, 0, stream>>>(x, wsb);
  swin_block_kernel<<<2048, 512, SMEM_BYTES, stream>>>(
      ls, proj_b, ln1w, ln1b, fc1b, fc2b, ln2w, ln2b, wsb);
  transpose_out_kernel<<<8192, 256, 0, stream>>>(wsb, out);
}

// Round 8
// 604.503 us; speedup vs baseline: 3.4918x; 1.0241x over previous
//
#include <hip/hip_runtime.h>
#include <hip/hip_bf16.h>

typedef __attribute__((ext_vector_type(4))) float f32x4;
typedef __attribute__((ext_vector_type(8))) short s16x8;
typedef __attribute__((ext_vector_type(4))) unsigned short u16x4;

// ---- LDS layout (byte offsets), total 163840 B (160 KiB, 1 block/CU) ----
// Attention phase:
#define L_XW   0        // bf16 [64][256] swzb rows 512B (dead after LN1 -> becomes H0)
#define L_SLAB 32768    // per head h at 32768+h*12288:
                        //   QK [64 tokens][128B] rows: q bytes 0..63 | k bytes 64..127
                        //   P  [64][128B] overwrites QK after S reads (same-wave ordering)
                        //   O  [64 tokens][64B] into P rows bytes 0..63 after PV reads
                        //   VT [32 d][128B] at +8192
#define L_NQ   131072   // f32 [8][64]: scale/|q_i|   (dead after attention -> H3)
#define L_NK   133120   // f32 [8][64]: 1/|k_j|
// Post-attention phase:
#define L_Y    32768    // bf16 [64][512B] swzb (over slabs h0..h2, after proj-read barrier)
#define L_H0   0
#define L_H1   65536
#define L_H2   98304
#define L_H3   131072
#define L_MB   65536    // fc2 out (over H1, after fc2-read barrier)
#define SMEM_BYTES 163840

// ---- workspace layout (byte offsets) ----
#define WSO_BIAS   0          // f32 [8][64][16][4] packed (h,i,c16,nt)   131072 B
#define WSO_QKVW   131072     // bf16 [48][32][16][8]       393216 B
#define WSO_PROJW  524288     // bf16 [16][32][16][8]       131072 B
#define WSO_FC1W   655360     // bf16 [64][32][16][8]       524288 B
#define WSO_FC2W   1179648    // bf16 [16][128][16][8]      524288 B
#define WSO_SIN    1703936ULL // bf16 [2][65536][256]       67108864 B
#define WSO_SOUT   68812800ULL// bf16 [2][65536][256]       67108864 B

__device__ __forceinline__ unsigned short f2bf(float f) {
  __hip_bfloat16 h = __float2bfloat16(f);
  return __builtin_bit_cast(unsigned short, h);
}
__device__ __forceinline__ float bf2f(unsigned short b) {
  union { unsigned u; float f; } v; v.u = ((unsigned)b) << 16;
  return v.f;
}
__device__ __forceinline__ int swzb(int row, int byteoff) {  // 128B+ rows, 8-way spread
  return byteoff ^ ((row & 7) << 4);
}

// ---------------- merged prep: weight pack + bias MLP + input transpose ----------------
__global__ __launch_bounds__(256)
void prep_kernel(const float* __restrict__ qkv_w,
                 const float* __restrict__ proj_w,
                 const float* __restrict__ fc1_w,
                 const float* __restrict__ fc2_w,
                 const float* __restrict__ cpb_w1,
                 const float* __restrict__ cpb_b1,
                 const float* __restrict__ cpb_w2,
                 const float* __restrict__ x,
                 unsigned char* __restrict__ wsb) {
  __shared__ float tile[64][66];
  const int bid = blockIdx.x;
  const int tid = threadIdx.x;

  if (bid < 3072) {
    // ---- weight pack to MFMA fragment layout ----
    int e = bid * 256 + tid;
    const float* src; unsigned short* dst; int K, N; int eo;
    if (e < 196608)       { eo = e;          src = qkv_w;  dst = (unsigned short*)(wsb + WSO_QKVW);  K = 256;  N = 768; }
    else if (e < 262144)  { eo = e - 196608; src = proj_w; dst = (unsigned short*)(wsb + WSO_PROJW); K = 256;  N = 256; }
    else if (e < 524288)  { eo = e - 262144; src = fc1_w;  dst = (unsigned short*)(wsb + WSO_FC1W);  K = 256;  N = 1024; }
    else                  { eo = e - 524288; src = fc2_w;  dst = (unsigned short*)(wsb + WSO_FC2W);  K = 1024; N = 256; }
    int j = eo & 7, c = (eo >> 3) & 15, rest = eo >> 7;
    int Kg = K >> 3;
    int kg = rest % Kg, nt = rest / Kg;
    dst[eo] = f2bf(src[(kg * 8 + j) * N + nt * 16 + c]);
  } else if (bid == 3072) {
    // ---- relative-position-bias via CPB MLP ----
    float (*bt)[8] = (float(*)[8])&tile[0][0];   // 225*8 floats fit in tile
    for (int t = tid; t < 225; t += 256) {
      int a = t / 15, b = t % 15;
      float r0 = (float)(a - 7) * (8.0f / 7.0f);
      float r1 = (float)(b - 7) * (8.0f / 7.0f);
      float f0 = (r0 >= 0.f ? 1.f : -1.f) * log2f(fabsf(r0) + 1.f) * (1.f / 3.f);
      float f1 = (r1 >= 0.f ? 1.f : -1.f) * log2f(fabsf(r1) + 1.f) * (1.f / 3.f);
      float acc[8] = {0.f,0.f,0.f,0.f,0.f,0.f,0.f,0.f};
      for (int k = 0; k < 512; ++k) {
        float hv = f0 * cpb_w1[k] + f1 * cpb_w1[512 + k] + cpb_b1[k];
        hv = fmaxf(hv, 0.f);
        #pragma unroll
        for (int h = 0; h < 8; ++h) acc[h] += hv * cpb_w2[k * 8 + h];
      }
      #pragma unroll
      for (int h = 0; h < 8; ++h) bt[t][h] = acc[h];
    }
    __syncthreads();
    float* biasp = (float*)(wsb + WSO_BIAS);
    for (int e = tid; e < 32768; e += 256) {
      int nn = e & 3, cc = (e >> 2) & 15, i = (e >> 6) & 63, h = e >> 12;
      int j = nn * 16 + cc;
      int dr = (i >> 3) - (j >> 3) + 7, dc = (i & 7) - (j & 7) + 7;
      float v = bt[dr * 15 + dc][h];
      biasp[e] = 16.f / (1.f + expf(-v));
    }
  } else {
    // ---- x[b][c][p] f32 -> sin[b][p][c] bf16 (tiled transpose) ----
    int b2 = bid - 3073;
    int pb = b2 & 1023;
    int cg = (b2 >> 10) & 3;
    int b  = b2 >> 12;
    int p0 = pb * 64, c0 = cg * 64;
    unsigned short* sg = (unsigned short*)(wsb + WSO_SIN);

    int pi = tid & 63, cq = tid >> 6;
    for (int r = 0; r < 16; ++r) {
      int c = cq * 16 + r;
      tile[pi][c] = x[((size_t)(b * 256 + c0 + c)) * 65536 + p0 + pi];
    }
    __syncthreads();
    int po = tid >> 2, co = tid & 3;
    s16x8 pk0, pk1;
    #pragma unroll
    for (int j = 0; j < 8; ++j) {
      pk0[j] = (short)f2bf(tile[po][co * 16 + j]);
      pk1[j] = (short)f2bf(tile[po][co * 16 + 8 + j]);
    }
    unsigned short* dp = sg + ((size_t)b * 65536 + p0 + po) * 256 + c0 + co * 16;
    *(s16x8*)(dp) = pk0;
    *(s16x8*)(dp + 8) = pk1;
  }
}

// ---------------- pass B: sout[b][p][c] bf16 -> out[b][c][p] f32 (tiled transpose) ----------------
__global__ __launch_bounds__(256)
void transpose_out_kernel(const unsigned char* __restrict__ wsb, float* __restrict__ out) {
  __shared__ float tile[64][65];
  int pb = blockIdx.x & 1023;
  int cg = (blockIdx.x >> 10) & 3;
  int b  = blockIdx.x >> 12;
  int p0 = pb * 64, c0 = cg * 64;
  int tid = threadIdx.x;
  const unsigned short* sg = (const unsigned short*)(wsb + WSO_SOUT);

  int pi = tid >> 2, cq = tid & 3;
  const unsigned short* rp = sg + ((size_t)b * 65536 + p0 + pi) * 256 + c0 + cq * 16;
  s16x8 a0 = *(const s16x8*)(rp);
  s16x8 a1 = *(const s16x8*)(rp + 8);
  #pragma unroll
  for (int j = 0; j < 8; ++j) {
    tile[pi][cq * 16 + j]     = bf2f((unsigned short)a0[j]);
    tile[pi][cq * 16 + 8 + j] = bf2f((unsigned short)a1[j]);
  }
  __syncthreads();
  int ci = tid >> 6, pi2 = tid & 63;
  for (int r = 0; r < 16; ++r) {
    int c = ci * 16 + r;
    out[((size_t)(b * 256 + c0 + c)) * 65536 + p0 + pi2] = tile[pi2][c];
  }
}

// ---------------- main fused per-window kernel: 512 threads / 8 waves, wave=head ----------------
// 2 waves/SIMD is the VGPR-file occupancy ceiling (rounds 4-6), so LDS spent freely (160 KiB).
// Attention stretch AND fc1 stretch are barrier-free; 128B-row slab keeps all LDS ops <=2-way.
__global__ __launch_bounds__(512, 2)
void swin_block_kernel(const float* __restrict__ ls,
                       const float* __restrict__ proj_b,
                       const float* __restrict__ ln1w, const float* __restrict__ ln1b,
                       const float* __restrict__ fc1b,
                       const float* __restrict__ fc2b,
                       const float* __restrict__ ln2w, const float* __restrict__ ln2b,
                       unsigned char* __restrict__ wsb) {
  extern __shared__ char sm[];
  const int tid = threadIdx.x;
  const int w = tid >> 6;       // wave id = head id in attention
  const int lane = tid & 63;
  const int g = lane >> 4;
  const int c16 = lane & 15;

  const int blk = blockIdx.x;
  const int bb = blk >> 10;
  const int widx = blk & 1023;
  const int wi = widx >> 5, wj = widx & 31;

  const f32x4* biasv = (const f32x4*)(wsb + WSO_BIAS);
  const unsigned short* qkvw = (const unsigned short*)(wsb + WSO_QKVW);
  const unsigned short* projw = (const unsigned short*)(wsb + WSO_PROJW);
  const unsigned short* fc1w = (const unsigned short*)(wsb + WSO_FC1W);
  const unsigned short* fc2w = (const unsigned short*)(wsb + WSO_FC2W);
  const unsigned short* sin_ = (const unsigned short*)(wsb + WSO_SIN);
  unsigned short* sout = (unsigned short*)(wsb + WSO_SOUT);

  // ---------- Phase 1: copy window from sin (channel-contiguous) -> XW bf16 swz ----------
  #pragma unroll
  for (int it = 0; it < 4; ++it) {
    int u = tid + it * 512;              // 16B units: u = t*32 + cu
    int t = u >> 5, cu = u & 31;
    int rp = (wi * 8 + (t >> 3) + 4) & 255;
    int cp = (wj * 8 + (t & 7) + 4) & 255;
    size_t pix = (size_t)bb * 65536 + rp * 256 + cp;
    s16x8 v = *(const s16x8*)(sin_ + pix * 256 + cu * 8);
    *(s16x8*)(sm + L_XW + t * 512 + swzb(t, cu * 16)) = v;
  }
  __syncthreads();   // B1

  char* const QB = sm + L_SLAB + w * 12288;   // this wave's head slab

  // ---------- Phase Q: qkv GEMM, wave w computes head w ----------
  {
    int tiles[6] = {2*w, 2*w+1, 16+2*w, 17+2*w, 32+2*w, 33+2*w};
    f32x4 acc[6][4];
    #pragma unroll
    for (int a = 0; a < 6; ++a)
      #pragma unroll
      for (int b = 0; b < 4; ++b) acc[a][b] = f32x4{0.f,0.f,0.f,0.f};
    #pragma unroll 2
    for (int k0 = 0; k0 < 256; k0 += 32) {
      s16x8 af[4];
      #pragma unroll
      for (int mt = 0; mt < 4; ++mt) {
        int row = mt * 16 + c16;
        af[mt] = *(const s16x8*)(sm + L_XW + row * 512 + swzb(row, (k0 + g * 8) * 2));
      }
      #pragma unroll
      for (int ct = 0; ct < 6; ++ct) {
        s16x8 bfr = *(const s16x8*)(qkvw + ((tiles[ct] * 32 + (k0 >> 3) + g) * 16 + c16) * 8);
        #pragma unroll
        for (int mt = 0; mt < 4; ++mt)
          acc[ct][mt] = __builtin_amdgcn_mfma_f32_16x16x32_bf16(af[mt], bfr, acc[ct][mt], 0, 0, 0);
      }
    }
    // epilogue: q|k -> QK rows (128B, 8-way swz); v transposed+permuted; norms from f32 acc
    float lsc = __expf(fminf(ls[w], 4.6051702f));
    float* nqp = (float*)(sm + L_NQ) + w * 64;
    float* nkp = (float*)(sm + L_NK) + w * 64;
    #pragma unroll
    for (int mt = 0; mt < 4; ++mt)
      #pragma unroll
      for (int r = 0; r < 4; ++r) {
        int i = mt * 16 + 4 * g + r;
        float sq = 0.f, sk = 0.f;
        #pragma unroll
        for (int dt = 0; dt < 2; ++dt) {
          float vq = acc[dt][mt][r];     sq += vq * vq;
          float vk = acc[2 + dt][mt][r]; sk += vk * vk;
          float vv = acc[4 + dt][mt][r];
          *(unsigned short*)(QB + i * 128 + swzb(i, (dt * 16 + c16) * 2)) = f2bf(vq);
          *(unsigned short*)(QB + i * 128 + swzb(i, 64 + (dt * 16 + c16) * 2)) = f2bf(vk);
          int d = dt * 16 + c16;
          int jp = 4 * (i & 15) + (i >> 4);     // permuted token index
          *(unsigned short*)(QB + 8192 + d * 128 + swzb(d, jp * 2)) = f2bf(vv);
        }
        sq += __shfl_xor(sq, 1); sq += __shfl_xor(sq, 2);
        sq += __shfl_xor(sq, 4); sq += __shfl_xor(sq, 8);
        sk += __shfl_xor(sk, 1); sk += __shfl_xor(sk, 2);
        sk += __shfl_xor(sk, 4); sk += __shfl_xor(sk, 8);
        if (c16 == 0) {
          nqp[i] = lsc / fmaxf(sqrtf(sq), 1e-12f);
          nkp[i] = 1.f / fmaxf(sqrtf(sk), 1e-12f);
        }
      }
  }
  // NO barrier: everything below (S, softmax, PV, O) is wave-private.

  // ---------- Phase A: S = q k^T, softmax(+bias+mask+norms), PV -> O ----------
  {
    s16x8 qf[4];
    #pragma unroll
    for (int mt = 0; mt < 4; ++mt) {
      int row = mt * 16 + c16;
      qf[mt] = *(const s16x8*)(QB + row * 128 + swzb(row, g * 16));
    }
    f32x4 S[4][4];
    #pragma unroll
    for (int nt = 0; nt < 4; ++nt) {
      int row = nt * 16 + c16;
      s16x8 kf = *(const s16x8*)(QB + row * 128 + swzb(row, 64 + g * 16));
      #pragma unroll
      for (int mt = 0; mt < 4; ++mt)
        S[mt][nt] = __builtin_amdgcn_mfma_f32_16x16x32_bf16(qf[mt], kf, f32x4{0.f,0.f,0.f,0.f}, 0, 0, 0);
    }
    // softmax per row (16 rows/thread), norms folded, P stored j-permuted (u16x4 packed)
    const float* nqp = (const float*)(sm + L_NQ) + w * 64;
    const float* nkp = (const float*)(sm + L_NK) + w * 64;
    float rk4[4];
    int labj[4];
    #pragma unroll
    for (int nt = 0; nt < 4; ++nt) {
      int jj = nt * 16 + c16;
      rk4[nt] = nkp[jj];
      int tr = jj >> 3, tc = jj & 7;
      labj[nt] = ((wi == 31) ? (tr >= 4 ? 2 : 1) : 0) * 3 + ((wj == 31) ? (tc >= 4 ? 2 : 1) : 0);
    }
    #pragma unroll
    for (int mt = 0; mt < 4; ++mt)
      #pragma unroll
      for (int r = 0; r < 4; ++r) {
        int i = mt * 16 + 4 * g + r;
        float rq = nqp[i];
        f32x4 bb4 = biasv[(w * 64 + i) * 16 + c16];
        int tr = i >> 3, tc = i & 7;
        int labi = ((wi == 31) ? (tr >= 4 ? 2 : 1) : 0) * 3 + ((wj == 31) ? (tc >= 4 ? 2 : 1) : 0);
        float vv[4];
        float mx = -1e30f;
        #pragma unroll
        for (int nt = 0; nt < 4; ++nt) {
          float v = S[mt][nt][r] * rq * rk4[nt] + bb4[nt];
          if (labi != labj[nt]) v -= 100.f;
          vv[nt] = v;
          mx = fmaxf(mx, v);
        }
        mx = fmaxf(mx, __shfl_xor(mx, 1));
        mx = fmaxf(mx, __shfl_xor(mx, 2));
        mx = fmaxf(mx, __shfl_xor(mx, 4));
        mx = fmaxf(mx, __shfl_xor(mx, 8));
        float sum = 0.f;
        #pragma unroll
        for (int nt = 0; nt < 4; ++nt) { vv[nt] = __expf(vv[nt] - mx); sum += vv[nt]; }
        sum += __shfl_xor(sum, 1);
        sum += __shfl_xor(sum, 2);
        sum += __shfl_xor(sum, 4);
        sum += __shfl_xor(sum, 8);
        float inv = 1.f / sum;
        u16x4 pk;
        #pragma unroll
        for (int nt = 0; nt < 4; ++nt) pk[nt] = f2bf(vv[nt] * inv);   // col' = 4*c16+nt
        *(u16x4*)(QB + i * 128 + swzb(i, c16 * 8)) = pk;              // over QK row i (reads done)
      }
    // PV: O = P @ V (j-permuted both operands), 16 MFMAs
    f32x4 O[4][2];
    #pragma unroll
    for (int a = 0; a < 4; ++a)
      #pragma unroll
      for (int b = 0; b < 2; ++b) O[a][b] = f32x4{0.f,0.f,0.f,0.f};
    #pragma unroll
    for (int k0 = 0; k0 < 64; k0 += 32) {
      s16x8 pf[4];
      #pragma unroll
      for (int mt = 0; mt < 4; ++mt) {
        int row = mt * 16 + c16;
        pf[mt] = *(const s16x8*)(QB + row * 128 + swzb(row, (k0 + g * 8) * 2));
      }
      #pragma unroll
      for (int nt = 0; nt < 2; ++nt) {
        int d = nt * 16 + c16;
        s16x8 vf = *(const s16x8*)(QB + 8192 + d * 128 + swzb(d, (k0 + g * 8) * 2));
        #pragma unroll
        for (int mt = 0; mt < 4; ++mt)
          O[mt][nt] = __builtin_amdgcn_mfma_f32_16x16x32_bf16(pf[mt], vf, O[mt][nt], 0, 0, 0);
      }
    }
    // O store into P rows bytes 0..63 (all P reads above are same-wave, DS in-order)
    #pragma unroll
    for (int mt = 0; mt < 4; ++mt)
      #pragma unroll
      for (int nt = 0; nt < 2; ++nt)
        #pragma unroll
        for (int r = 0; r < 4; ++r) {
          int i = mt * 16 + 4 * g + r;
          int d = nt * 16 + c16;
          *(unsigned short*)(QB + i * 128 + swzb(i, d * 2)) = f2bf(O[mt][nt][r]);
        }
  }
  __syncthreads();   // B2: all heads' O complete

  // ---------- Phase P: proj (K = 8 heads x 32), wave w -> col-tiles 2w, 2w+1 ----------
  {
    f32x4 aP[2][4];
    #pragma unroll
    for (int a = 0; a < 2; ++a)
      #pragma unroll
      for (int b = 0; b < 4; ++b) aP[a][b] = f32x4{0.f,0.f,0.f,0.f};
    #pragma unroll 2
    for (int k0 = 0; k0 < 256; k0 += 32) {
      int hk = k0 >> 5;
      const char* OBk = sm + L_SLAB + hk * 12288;
      s16x8 af[4];
      #pragma unroll
      for (int mt = 0; mt < 4; ++mt) {
        int row = mt * 16 + c16;
        af[mt] = *(const s16x8*)(OBk + row * 128 + swzb(row, g * 16));
      }
      #pragma unroll
      for (int t2 = 0; t2 < 2; ++t2) {
        s16x8 bfr = *(const s16x8*)(projw + (((2*w + t2) * 32 + 4*hk + g) * 16 + c16) * 8);
        #pragma unroll
        for (int mt = 0; mt < 4; ++mt)
          aP[t2][mt] = __builtin_amdgcn_mfma_f32_16x16x32_bf16(af[mt], bfr, aP[t2][mt], 0, 0, 0);
      }
    }
    __syncthreads();   // B3: O reads done before Y (aliased region) writes
    #pragma unroll
    for (int t2 = 0; t2 < 2; ++t2) {
      int col = (2*w + t2) * 16 + c16;
      float pb = proj_b[col];
      #pragma unroll
      for (int mt = 0; mt < 4; ++mt)
        #pragma unroll
        for (int r = 0; r < 4; ++r) {
          int i = mt * 16 + 4 * g + r;
          *(unsigned short*)(sm + L_Y + i * 512 + swzb(i, col * 2)) = f2bf(aP[t2][mt][r] + pb);
        }
    }
  }
  __syncthreads();   // B4

  // ---------- LN1 + residual: y = LN(o)*g+b + xw, in place on Y; 8 lanes/row ----------
  {
    int t = tid >> 3, oc = tid & 7;
    float v[32];
    float s1 = 0.f;
    #pragma unroll
    for (int b2 = 0; b2 < 4; ++b2) {
      s16x8 vb = *(const s16x8*)(sm + L_Y + t * 512 + swzb(t, oc * 64 + b2 * 16));
      #pragma unroll
      for (int e = 0; e < 8; ++e) { float fv = bf2f((unsigned short)vb[e]); v[b2*8+e] = fv; s1 += fv; }
    }
    s1 += __shfl_xor(s1, 1);
    s1 += __shfl_xor(s1, 2);
    s1 += __shfl_xor(s1, 4);
    float mu = s1 * (1.f / 256.f);
    float s2 = 0.f;
    #pragma unroll
    for (int e = 0; e < 32; ++e) { float d = v[e] - mu; s2 += d * d; }
    s2 += __shfl_xor(s2, 1);
    s2 += __shfl_xor(s2, 2);
    s2 += __shfl_xor(s2, 4);
    float rs = rsqrtf(s2 * (1.f / 256.f) + 1e-5f);
    #pragma unroll
    for (int b2 = 0; b2 < 4; ++b2) {
      s16x8 xb = *(const s16x8*)(sm + L_XW + t * 512 + swzb(t, oc * 64 + b2 * 16));
      s16x8 yb;
      #pragma unroll
      for (int e = 0; e < 8; ++e) {
        int c = oc * 32 + b2 * 8 + e;
        float yv = (v[b2*8+e] - mu) * rs * ln1w[c] + ln1b[c] + bf2f((unsigned short)xb[e]);
        yb[e] = (short)f2bf(yv);
      }
      *(s16x8*)(sm + L_Y + t * 512 + swzb(t, oc * 64 + b2 * 16)) = yb;
    }
  }
  __syncthreads();   // B5: Y final; XW dead (H0 may overwrite)

  // ---------- MLP fc1: all 4 chunks, BARRIER-FREE (disjoint H buffers, reads only Y) ----------
  {
    const int Hoff[4] = {L_H0, L_H1, L_H2, L_H3};
    #pragma unroll 1
    for (int cc = 0; cc < 4; ++cc) {
      char* HB = sm + Hoff[cc];
      f32x4 acc1[2][4];
      #pragma unroll
      for (int a = 0; a < 2; ++a)
        #pragma unroll
        for (int b = 0; b < 4; ++b) acc1[a][b] = f32x4{0.f,0.f,0.f,0.f};
      for (int k0 = 0; k0 < 256; k0 += 32) {
        s16x8 af[4];
        #pragma unroll
        for (int mt = 0; mt < 4; ++mt) {
          int row = mt * 16 + c16;
          af[mt] = *(const s16x8*)(sm + L_Y + row * 512 + swzb(row, (k0 + g * 8) * 2));
        }
        #pragma unroll
        for (int t2 = 0; t2 < 2; ++t2) {
          int gt = cc * 16 + 2*w + t2;
          s16x8 bfr = *(const s16x8*)(fc1w + ((gt * 32 + (k0 >> 3) + g) * 16 + c16) * 8);
          #pragma unroll
          for (int mt = 0; mt < 4; ++mt)
            acc1[t2][mt] = __builtin_amdgcn_mfma_f32_16x16x32_bf16(af[mt], bfr, acc1[t2][mt], 0, 0, 0);
        }
      }
      // gelu (tanh form) + store H chunk
      #pragma unroll
      for (int t2 = 0; t2 < 2; ++t2) {
        int coll = (2*w + t2) * 16 + c16;
        float b1v = fc1b[cc * 256 + coll];
        #pragma unroll
        for (int mt = 0; mt < 4; ++mt)
          #pragma unroll
          for (int r = 0; r < 4; ++r) {
            int i = mt * 16 + 4 * g + r;
            float u = acc1[t2][mt][r] + b1v;
            float z = 0.7978845608f * u * (1.f + 0.044715f * u * u);
            float e2 = __expf(2.f * z);
            float ge = u * e2 / (e2 + 1.f);
            *(unsigned short*)(HB + i * 512 + swzb(i, coll * 2)) = f2bf(ge);
          }
      }
    }
  }
  __syncthreads();   // B6: all H complete

  // ---------- MLP fc2: one barrier-free pass over K=1024 ----------
  f32x4 acc2[2][4];
  #pragma unroll
  for (int a = 0; a < 2; ++a)
    #pragma unroll
    for (int b = 0; b < 4; ++b) acc2[a][b] = f32x4{0.f,0.f,0.f,0.f};
  {
    const int Hoff[4] = {L_H0, L_H1, L_H2, L_H3};
    #pragma unroll 1
    for (int cc = 0; cc < 4; ++cc) {
      const char* HB = sm + Hoff[cc];
      for (int k0 = 0; k0 < 256; k0 += 32) {
        s16x8 af[4];
        #pragma unroll
        for (int mt = 0; mt < 4; ++mt) {
          int row = mt * 16 + c16;
          af[mt] = *(const s16x8*)(HB + row * 512 + swzb(row, (k0 + g * 8) * 2));
        }
        #pragma unroll
        for (int t2 = 0; t2 < 2; ++t2) {
          int kg = cc * 32 + (k0 >> 3) + g;
          s16x8 bfr = *(const s16x8*)(fc2w + (((2*w + t2) * 128 + kg) * 16 + c16) * 8);
          #pragma unroll
          for (int mt = 0; mt < 4; ++mt)
            acc2[t2][mt] = __builtin_amdgcn_mfma_f32_16x16x32_bf16(af[mt], bfr, acc2[t2][mt], 0, 0, 0);
        }
      }
    }
  }
  __syncthreads();   // B7: all fc2 H reads done (MB overwrites H1)

  // ---------- fc2 epilogue -> MB ----------
  #pragma unroll
  for (int t2 = 0; t2 < 2; ++t2) {
    int col = (2*w + t2) * 16 + c16;
    float b2v = fc2b[col];
    #pragma unroll
    for (int mt = 0; mt < 4; ++mt)
      #pragma unroll
      for (int r = 0; r < 4; ++r) {
        int i = mt * 16 + 4 * g + r;
        *(unsigned short*)(sm + L_MB + i * 512 + swzb(i, col * 2)) = f2bf(acc2[t2][mt][r] + b2v);
      }
  }
  __syncthreads();   // B8

  // ---------- LN2 + residual; direct bf16 store to sout (64B/thread contiguous) ----------
  {
    int t2 = tid >> 3, oc = tid & 7;
    float v[32];
    float s1 = 0.f;
    #pragma unroll
    for (int b2 = 0; b2 < 4; ++b2) {
      s16x8 vb = *(const s16x8*)(sm + L_MB + t2 * 512 + swzb(t2, oc * 64 + b2 * 16));
      #pragma unroll
      for (int e = 0; e < 8; ++e) { float fv = bf2f((unsigned short)vb[e]); v[b2*8+e] = fv; s1 += fv; }
    }
    s1 += __shfl_xor(s1, 1);
    s1 += __shfl_xor(s1, 2);
    s1 += __shfl_xor(s1, 4);
    float mu = s1 * (1.f / 256.f);
    float s2 = 0.f;
    #pragma unroll
    for (int e = 0; e < 32; ++e) { float d = v[e] - mu; s2 += d * d; }
    s2 += __shfl_xor(s2, 1);
    s2 += __shfl_xor(s2, 2);
    s2 += __shfl_xor(s2, 4);
    float rs = rsqrtf(s2 * (1.f / 256.f) + 1e-5f);
    int rp = (wi * 8 + (t2 >> 3) + 4) & 255;
    int cp = (wj * 8 + (t2 & 7) + 4) & 255;
    size_t pix = (size_t)bb * 65536 + rp * 256 + cp;
    unsigned short* so = sout + pix * 256 + oc * 32;
    #pragma unroll
    for (int b2 = 0; b2 < 4; ++b2) {
      s16x8 yb = *(const s16x8*)(sm + L_Y + t2 * 512 + swzb(t2, oc * 64 + b2 * 16));
      s16x8 pk;
      #pragma unroll
      for (int e = 0; e < 8; ++e) {
        int c = oc * 32 + b2 * 8 + e;
        float yv = (v[b2*8+e] - mu) * rs * ln2w[c] + ln2b[c] + bf2f((unsigned short)yb[e]);
        pk[e] = (short)f2bf(yv);
      }
      *(s16x8*)(so + b2 * 8) = pk;
    }
  }
}

extern "C" void kernel_launch(void* const* d_in, const int* in_sizes, int n_in,
                              void* d_out, int out_size, void* d_ws, size_t ws_size,
                              hipStream_t stream) {
  const float* x      = (const float*)d_in[0];
  const float* qkv_w  = (const float*)d_in[1];
  const float* ls     = (const float*)d_in[2];
  const float* proj_w = (const float*)d_in[3];
  const float* proj_b = (const float*)d_in[4];
  const float* ln1w   = (const float*)d_in[5];
  const float* ln1b   = (const float*)d_in[6];
  const float* fc1_w  = (const float*)d_in[7];
  const float* fc1b   = (const float*)d_in[8];
  const float* fc2_w  = (const float*)d_in[9];
  const float* fc2b   = (const float*)d_in[10];
  const float* ln2w   = (const float*)d_in[11];
  const float* ln2b   = (const float*)d_in[12];
  const float* cpb_w1 = (const float*)d_in[13];
  const float* cpb_b1 = (const float*)d_in[14];
  const float* cpb_w2 = (const float*)d_in[15];
  unsigned char* wsb = (unsigned char*)d_ws;
  float* out = (float*)d_out;

  hipFuncSetAttribute(reinterpret_cast<const void*>(swin_block_kernel),
                      hipFuncAttributeMaxDynamicSharedMemorySize, SMEM_BYTES);

  prep_kernel<<<11265, 256, 0, stream>>>(qkv_w, proj_w, fc1_w, fc2_w,
                                         cpb_w1, cpb_b1, cpb_w2, x, wsb);
  swin_block_kernel<<<2048, 512, SMEM_BYTES, stream>>>(
      ls, proj_b, ln1w, ln1b, fc1b, fc2b, ln2w, ln2b, wsb);
  transpose_out_kernel<<<8192, 256, 0, stream>>>(wsb, out);
}

// Round 9
// 533.957 us; speedup vs baseline: 3.9531x; 1.1321x over previous
//
#include <hip/hip_runtime.h>
#include <hip/hip_bf16.h>

typedef __attribute__((ext_vector_type(4))) float f32x4;
typedef __attribute__((ext_vector_type(8))) short s16x8;
typedef __attribute__((ext_vector_type(4))) unsigned short u16x4;

// ---- LDS layout (byte offsets), total 163840 B (160 KiB, 1 block/CU) ----
#define L_XW   0        // bf16 [64][256] swzb rows 512B (dead after LN1 -> H0)
#define L_SLAB 32768    // per head h at 32768+h*12288:
                        //   QK [64 tokens][128B]: q-packed bytes 0..63 | k-packed 64..127
                        //   P~ [64][128B] overwrites QK after S reads (same-wave order)
                        //   O  packed into P rows bytes 0..63 after PV reads
                        //   VT [32 d][128B] at +8192 (j-permuted)
#define L_NQ   131072   // f32 [8][64]: lsc/|q_i|   (dead after attention -> H3)
#define L_NK   133120   // f32 [8][64]: 1/|k_j|
#define L_Y    32768    // bf16 [64][512B] swzb (over slabs h0..h2 after proj barrier)
#define L_H0   0
#define L_H1   65536
#define L_H2   98304
#define L_H3   131072
#define L_MB   65536    // fc2 out (over H1, after fc2-read barrier)
#define SMEM_BYTES 163840

// ---- workspace layout (byte offsets) ----
#define WSO_BIAS   0          // f32 [8][64][16][4] packed (h,i,c16,nt), MINUS (scale_h+16)
#define WSO_QKVW   131072     // bf16 [48][32][16][8]       393216 B
#define WSO_PROJW  524288     // bf16 [16][32][16][8]  (K d-permuted per 32-group)
#define WSO_FC1W   655360     // bf16 [64][32][16][8]       524288 B
#define WSO_FC2W   1179648    // bf16 [16][128][16][8] (K d-permuted per 32-group)
#define WSO_SIN    1703936ULL // bf16 [2][65536][256]       67108864 B
#define WSO_SOUT   68812800ULL// bf16 [2][65536][256]       67108864 B

__device__ __forceinline__ unsigned short f2bf(float f) {
  __hip_bfloat16 h = __float2bfloat16(f);
  return __builtin_bit_cast(unsigned short, h);
}
__device__ __forceinline__ float bf2f(unsigned short b) {
  union { unsigned u; float f; } v; v.u = ((unsigned)b) << 16;
  return v.f;
}
__device__ __forceinline__ int swzb(int row, int byteoff) {  // 128B+ rows, 8-way spread
  return byteoff ^ ((row & 7) << 4);
}

// ---------------- merged prep: weight pack + bias MLP + input transpose ----------------
__global__ __launch_bounds__(256)
void prep_kernel(const float* __restrict__ qkv_w,
                 const float* __restrict__ proj_w,
                 const float* __restrict__ fc1_w,
                 const float* __restrict__ fc2_w,
                 const float* __restrict__ cpb_w1,
                 const float* __restrict__ cpb_b1,
                 const float* __restrict__ cpb_w2,
                 const float* __restrict__ x,
                 const float* __restrict__ ls,
                 unsigned char* __restrict__ wsb) {
  __shared__ float tile[64][66];
  const int bid = blockIdx.x;
  const int tid = threadIdx.x;

  if (bid < 3072) {
    // ---- weight pack to MFMA fragment layout (proj/fc2: K d-perm per 32-group) ----
    int e = bid * 256 + tid;
    const float* src; unsigned short* dst; int K, N; int eo; bool perm;
    if (e < 196608)       { eo = e;          src = qkv_w;  dst = (unsigned short*)(wsb + WSO_QKVW);  K = 256;  N = 768;  perm = false; }
    else if (e < 262144)  { eo = e - 196608; src = proj_w; dst = (unsigned short*)(wsb + WSO_PROJW); K = 256;  N = 256;  perm = true; }
    else if (e < 524288)  { eo = e - 262144; src = fc1_w;  dst = (unsigned short*)(wsb + WSO_FC1W);  K = 256;  N = 1024; perm = false; }
    else                  { eo = e - 524288; src = fc2_w;  dst = (unsigned short*)(wsb + WSO_FC2W);  K = 1024; N = 256;  perm = true; }
    int j = eo & 7, c = (eo >> 3) & 15, rest = eo >> 7;
    int Kg = K >> 3;
    int kg = rest % Kg, nt = rest / Kg;
    int s = kg * 8 + j;
    if (perm) s = (s & ~31) | ((s & 1) << 4) | ((s & 31) >> 1);   // slot -> original d
    dst[eo] = f2bf(src[s * N + nt * 16 + c]);
  } else if (bid == 3072) {
    // ---- relative-position-bias via CPB MLP, with -(scale_h+16) baked ----
    float (*bt)[8] = (float(*)[8])&tile[0][0];
    for (int t = tid; t < 225; t += 256) {
      int a = t / 15, b = t % 15;
      float r0 = (float)(a - 7) * (8.0f / 7.0f);
      float r1 = (float)(b - 7) * (8.0f / 7.0f);
      float f0 = (r0 >= 0.f ? 1.f : -1.f) * log2f(fabsf(r0) + 1.f) * (1.f / 3.f);
      float f1 = (r1 >= 0.f ? 1.f : -1.f) * log2f(fabsf(r1) + 1.f) * (1.f / 3.f);
      float acc[8] = {0.f,0.f,0.f,0.f,0.f,0.f,0.f,0.f};
      for (int k = 0; k < 512; ++k) {
        float hv = f0 * cpb_w1[k] + f1 * cpb_w1[512 + k] + cpb_b1[k];
        hv = fmaxf(hv, 0.f);
        #pragma unroll
        for (int h = 0; h < 8; ++h) acc[h] += hv * cpb_w2[k * 8 + h];
      }
      #pragma unroll
      for (int h = 0; h < 8; ++h) bt[t][h] = acc[h];
    }
    __syncthreads();
    float* biasp = (float*)(wsb + WSO_BIAS);
    for (int e = tid; e < 32768; e += 256) {
      int nn = e & 3, cc = (e >> 2) & 15, i = (e >> 6) & 63, h = e >> 12;
      int j = nn * 16 + cc;
      int dr = (i >> 3) - (j >> 3) + 7, dc = (i & 7) - (j & 7) + 7;
      float v = bt[dr * 15 + dc][h];
      float scale = __expf(fminf(ls[h], 4.6051702f));
      biasp[e] = 16.f / (1.f + expf(-v)) - (scale + 16.f);  // bound: logit <= scale+16
    }
  } else {
    // ---- x[b][c][p] f32 -> sin[b][p][c] bf16 (tiled transpose) ----
    int b2 = bid - 3073;
    int pb = b2 & 1023;
    int cg = (b2 >> 10) & 3;
    int b  = b2 >> 12;
    int p0 = pb * 64, c0 = cg * 64;
    unsigned short* sg = (unsigned short*)(wsb + WSO_SIN);

    int pi = tid & 63, cq = tid >> 6;
    for (int r = 0; r < 16; ++r) {
      int c = cq * 16 + r;
      tile[pi][c] = x[((size_t)(b * 256 + c0 + c)) * 65536 + p0 + pi];
    }
    __syncthreads();
    int po = tid >> 2, co = tid & 3;
    s16x8 pk0, pk1;
    #pragma unroll
    for (int j = 0; j < 8; ++j) {
      pk0[j] = (short)f2bf(tile[po][co * 16 + j]);
      pk1[j] = (short)f2bf(tile[po][co * 16 + 8 + j]);
    }
    unsigned short* dp = sg + ((size_t)b * 65536 + p0 + po) * 256 + c0 + co * 16;
    *(s16x8*)(dp) = pk0;
    *(s16x8*)(dp + 8) = pk1;
  }
}

// ---------------- pass B: sout[b][p][c] bf16 -> out[b][c][p] f32 (tiled transpose) ----------------
__global__ __launch_bounds__(256)
void transpose_out_kernel(const unsigned char* __restrict__ wsb, float* __restrict__ out) {
  __shared__ float tile[64][65];
  int pb = blockIdx.x & 1023;
  int cg = (blockIdx.x >> 10) & 3;
  int b  = blockIdx.x >> 12;
  int p0 = pb * 64, c0 = cg * 64;
  int tid = threadIdx.x;
  const unsigned short* sg = (const unsigned short*)(wsb + WSO_SOUT);

  int pi = tid >> 2, cq = tid & 3;
  const unsigned short* rp = sg + ((size_t)b * 65536 + p0 + pi) * 256 + c0 + cq * 16;
  s16x8 a0 = *(const s16x8*)(rp);
  s16x8 a1 = *(const s16x8*)(rp + 8);
  #pragma unroll
  for (int j = 0; j < 8; ++j) {
    tile[pi][cq * 16 + j]     = bf2f((unsigned short)a0[j]);
    tile[pi][cq * 16 + 8 + j] = bf2f((unsigned short)a1[j]);
  }
  __syncthreads();
  int ci = tid >> 6, pi2 = tid & 63;
  for (int r = 0; r < 16; ++r) {
    int c = ci * 16 + r;
    out[((size_t)(b * 256 + c0 + c)) * 65536 + p0 + pi2] = tile[pi2][c];
  }
}

// ---------------- main fused per-window kernel: 512 threads / 8 waves, wave=head ----------------
__global__ __launch_bounds__(512, 2)
void swin_block_kernel(const float* __restrict__ ls,
                       const float* __restrict__ proj_b,
                       const float* __restrict__ ln1w, const float* __restrict__ ln1b,
                       const float* __restrict__ fc1b,
                       const float* __restrict__ fc2b,
                       const float* __restrict__ ln2w, const float* __restrict__ ln2b,
                       unsigned char* __restrict__ wsb) {
  extern __shared__ char sm[];
  const int tid = threadIdx.x;
  const int w = tid >> 6;       // wave id = head id in attention
  const int lane = tid & 63;
  const int g = lane >> 4;
  const int c16 = lane & 15;

  const int blk = blockIdx.x;
  const int bb = blk >> 10;
  const int widx = blk & 1023;
  const int wi = widx >> 5, wj = widx & 31;

  const f32x4* biasv = (const f32x4*)(wsb + WSO_BIAS);
  const unsigned short* qkvw = (const unsigned short*)(wsb + WSO_QKVW);
  const unsigned short* projw = (const unsigned short*)(wsb + WSO_PROJW);
  const unsigned short* fc1w = (const unsigned short*)(wsb + WSO_FC1W);
  const unsigned short* fc2w = (const unsigned short*)(wsb + WSO_FC2W);
  const unsigned short* sin_ = (const unsigned short*)(wsb + WSO_SIN);
  unsigned short* sout = (unsigned short*)(wsb + WSO_SOUT);

  // ---------- Phase 1: copy window from sin -> XW bf16 swz ----------
  #pragma unroll
  for (int it = 0; it < 4; ++it) {
    int u = tid + it * 512;
    int t = u >> 5, cu = u & 31;
    int rp = (wi * 8 + (t >> 3) + 4) & 255;
    int cp = (wj * 8 + (t & 7) + 4) & 255;
    size_t pix = (size_t)bb * 65536 + rp * 256 + cp;
    s16x8 v = *(const s16x8*)(sin_ + pix * 256 + cu * 8);
    *(s16x8*)(sm + L_XW + t * 512 + swzb(t, cu * 16)) = v;
  }
  __syncthreads();   // B1

  char* const QB = sm + L_SLAB + w * 12288;

  // ---------- Phase Q: qkv GEMM, wave w computes head w ----------
  {
    int tiles[6] = {2*w, 2*w+1, 16+2*w, 17+2*w, 32+2*w, 33+2*w};
    f32x4 acc[6][4];
    #pragma unroll
    for (int a = 0; a < 6; ++a)
      #pragma unroll
      for (int b = 0; b < 4; ++b) acc[a][b] = f32x4{0.f,0.f,0.f,0.f};
    #pragma unroll 2
    for (int k0 = 0; k0 < 256; k0 += 32) {
      s16x8 af[4];
      #pragma unroll
      for (int mt = 0; mt < 4; ++mt) {
        int row = mt * 16 + c16;
        af[mt] = *(const s16x8*)(sm + L_XW + row * 512 + swzb(row, (k0 + g * 8) * 2));
      }
      #pragma unroll
      for (int ct = 0; ct < 6; ++ct) {
        s16x8 bfr = *(const s16x8*)(qkvw + ((tiles[ct] * 32 + (k0 >> 3) + g) * 16 + c16) * 8);
        #pragma unroll
        for (int mt = 0; mt < 4; ++mt)
          acc[ct][mt] = __builtin_amdgcn_mfma_f32_16x16x32_bf16(af[mt], bfr, acc[ct][mt], 0, 0, 0);
      }
    }
    // epilogue: q,k packed-b32 (d' = 2*(d&15)+(d>>4)); v transposed+j-permuted
    #pragma unroll
    for (int mt = 0; mt < 4; ++mt)
      #pragma unroll
      for (int r = 0; r < 4; ++r) {
        int i = mt * 16 + 4 * g + r;
        unsigned uq = (unsigned)f2bf(acc[0][mt][r]) | ((unsigned)f2bf(acc[1][mt][r]) << 16);
        unsigned uk = (unsigned)f2bf(acc[2][mt][r]) | ((unsigned)f2bf(acc[3][mt][r]) << 16);
        *(unsigned*)(QB + i * 128 + swzb(i, c16 * 4)) = uq;
        *(unsigned*)(QB + i * 128 + swzb(i, 64 + c16 * 4)) = uk;
        int jp = 4 * (i & 15) + (i >> 4);
        *(unsigned short*)(QB + 8192 + c16 * 128 + swzb(c16, jp * 2)) = f2bf(acc[4][mt][r]);
        *(unsigned short*)(QB + 8192 + (16 + c16) * 128 + swzb(16 + c16, jp * 2)) = f2bf(acc[5][mt][r]);
      }
  }
  // norm pass (wave-private; DS in-order): lane reads q-row `lane` and k-row `lane`
  {
    float lsc = __expf(fminf(ls[w], 4.6051702f));
    float sq = 0.f, sk2 = 0.f;
    #pragma unroll
    for (int cc4 = 0; cc4 < 4; ++cc4) {
      s16x8 qv = *(const s16x8*)(QB + lane * 128 + swzb(lane, cc4 * 16));
      s16x8 kv = *(const s16x8*)(QB + lane * 128 + swzb(lane, 64 + cc4 * 16));
      #pragma unroll
      for (int e = 0; e < 8; ++e) {
        float a = bf2f((unsigned short)qv[e]); sq  += a * a;
        float b = bf2f((unsigned short)kv[e]); sk2 += b * b;
      }
    }
    ((float*)(sm + L_NQ))[w * 64 + lane] = lsc * rsqrtf(fmaxf(sq, 1e-24f));
    ((float*)(sm + L_NK))[w * 64 + lane] = rsqrtf(fmaxf(sk2, 1e-24f));
  }

  // ---------- Phase A: S, bounded-exp softmax (no reductions), PV + MFMA row-sums ----------
  {
    s16x8 qf[4];
    #pragma unroll
    for (int mt = 0; mt < 4; ++mt) {
      int row = mt * 16 + c16;
      qf[mt] = *(const s16x8*)(QB + row * 128 + swzb(row, g * 16));
    }
    f32x4 S[4][4];
    #pragma unroll
    for (int nt = 0; nt < 4; ++nt) {
      int row = nt * 16 + c16;
      s16x8 kf = *(const s16x8*)(QB + row * 128 + swzb(row, 64 + g * 16));
      #pragma unroll
      for (int mt = 0; mt < 4; ++mt)
        S[mt][nt] = __builtin_amdgcn_mfma_f32_16x16x32_bf16(qf[mt], kf, f32x4{0.f,0.f,0.f,0.f}, 0, 0, 0);
    }
    const float* nqp = (const float*)(sm + L_NQ) + w * 64;
    const float* nkp = (const float*)(sm + L_NK) + w * 64;
    float rk4[4];
    #pragma unroll
    for (int nt = 0; nt < 4; ++nt) rk4[nt] = nkp[nt * 16 + c16];

    const bool edge = (wi == 31) || (wj == 31);
    if (edge) {
      int labj[4];
      #pragma unroll
      for (int nt = 0; nt < 4; ++nt) {
        int jj = nt * 16 + c16;
        int tr = jj >> 3, tc = jj & 7;
        labj[nt] = ((wi == 31) ? (tr >= 4 ? 2 : 1) : 0) * 3 + ((wj == 31) ? (tc >= 4 ? 2 : 1) : 0);
      }
      #pragma unroll
      for (int mt = 0; mt < 4; ++mt)
        #pragma unroll
        for (int r = 0; r < 4; ++r) {
          int i = mt * 16 + 4 * g + r;
          float rq = nqp[i];
          f32x4 bb4 = biasv[(w * 64 + i) * 16 + c16];
          int tr = i >> 3, tc = i & 7;
          int labi = ((wi == 31) ? (tr >= 4 ? 2 : 1) : 0) * 3 + ((wj == 31) ? (tc >= 4 ? 2 : 1) : 0);
          u16x4 pk;
          #pragma unroll
          for (int nt = 0; nt < 4; ++nt) {
            float vx = fmaf(S[mt][nt][r] * rk4[nt], rq, bb4[nt]);
            if (labi != labj[nt]) vx -= 100.f;
            pk[nt] = f2bf(__expf(vx));
          }
          *(u16x4*)(QB + i * 128 + swzb(i, c16 * 8)) = pk;
        }
    } else {
      #pragma unroll
      for (int mt = 0; mt < 4; ++mt)
        #pragma unroll
        for (int r = 0; r < 4; ++r) {
          int i = mt * 16 + 4 * g + r;
          float rq = nqp[i];
          f32x4 bb4 = biasv[(w * 64 + i) * 16 + c16];
          u16x4 pk;
          #pragma unroll
          for (int nt = 0; nt < 4; ++nt) {
            float vx = fmaf(S[mt][nt][r] * rk4[nt], rq, bb4[nt]);
            pk[nt] = f2bf(__expf(vx));
          }
          *(u16x4*)(QB + i * 128 + swzb(i, c16 * 8)) = pk;
        }
    }

    // PV + rowsum-via-ones: O_raw = P~ @ V ; RS = P~ @ 1 (lands in matching lanes)
    s16x8 ones;
    #pragma unroll
    for (int e = 0; e < 8; ++e) ones[e] = (short)0x3F80;
    f32x4 O[4][2], RS[4];
    #pragma unroll
    for (int a = 0; a < 4; ++a) {
      O[a][0] = f32x4{0.f,0.f,0.f,0.f};
      O[a][1] = f32x4{0.f,0.f,0.f,0.f};
      RS[a]   = f32x4{0.f,0.f,0.f,0.f};
    }
    #pragma unroll
    for (int k0 = 0; k0 < 64; k0 += 32) {
      s16x8 pf[4];
      #pragma unroll
      for (int mt = 0; mt < 4; ++mt) {
        int row = mt * 16 + c16;
        pf[mt] = *(const s16x8*)(QB + row * 128 + swzb(row, (k0 + g * 8) * 2));
      }
      #pragma unroll
      for (int nt = 0; nt < 2; ++nt) {
        int d = nt * 16 + c16;
        s16x8 vf = *(const s16x8*)(QB + 8192 + d * 128 + swzb(d, (k0 + g * 8) * 2));
        #pragma unroll
        for (int mt = 0; mt < 4; ++mt)
          O[mt][nt] = __builtin_amdgcn_mfma_f32_16x16x32_bf16(pf[mt], vf, O[mt][nt], 0, 0, 0);
      }
      #pragma unroll
      for (int mt = 0; mt < 4; ++mt)
        RS[mt] = __builtin_amdgcn_mfma_f32_16x16x32_bf16(pf[mt], ones, RS[mt], 0, 0, 0);
    }
    // normalize + packed O store into P rows bytes 0..63 (d' pairing; P reads done)
    #pragma unroll
    for (int mt = 0; mt < 4; ++mt)
      #pragma unroll
      for (int r = 0; r < 4; ++r) {
        float inv = __builtin_amdgcn_rcpf(fmaxf(RS[mt][r], 1e-35f));
        int i = mt * 16 + 4 * g + r;
        unsigned u = (unsigned)f2bf(O[mt][0][r] * inv) | ((unsigned)f2bf(O[mt][1][r] * inv) << 16);
        *(unsigned*)(QB + i * 128 + swzb(i, c16 * 4)) = u;
      }
  }
  __syncthreads();   // B2: all heads' O complete

  // ---------- Phase P: proj (K = 8 heads x 32, d-perm baked in projw) ----------
  {
    f32x4 aP[2][4];
    #pragma unroll
    for (int a = 0; a < 2; ++a)
      #pragma unroll
      for (int b = 0; b < 4; ++b) aP[a][b] = f32x4{0.f,0.f,0.f,0.f};
    #pragma unroll 2
    for (int k0 = 0; k0 < 256; k0 += 32) {
      int hk = k0 >> 5;
      const char* OBk = sm + L_SLAB + hk * 12288;
      s16x8 af[4];
      #pragma unroll
      for (int mt = 0; mt < 4; ++mt) {
        int row = mt * 16 + c16;
        af[mt] = *(const s16x8*)(OBk + row * 128 + swzb(row, g * 16));
      }
      #pragma unroll
      for (int t2 = 0; t2 < 2; ++t2) {
        s16x8 bfr = *(const s16x8*)(projw + (((2*w + t2) * 32 + 4*hk + g) * 16 + c16) * 8);
        #pragma unroll
        for (int mt = 0; mt < 4; ++mt)
          aP[t2][mt] = __builtin_amdgcn_mfma_f32_16x16x32_bf16(af[mt], bfr, aP[t2][mt], 0, 0, 0);
      }
    }
    __syncthreads();   // B3: O reads done before Y (aliased region) writes
    #pragma unroll
    for (int t2 = 0; t2 < 2; ++t2) {
      int col = (2*w + t2) * 16 + c16;
      float pb = proj_b[col];
      #pragma unroll
      for (int mt = 0; mt < 4; ++mt)
        #pragma unroll
        for (int r = 0; r < 4; ++r) {
          int i = mt * 16 + 4 * g + r;
          *(unsigned short*)(sm + L_Y + i * 512 + swzb(i, col * 2)) = f2bf(aP[t2][mt][r] + pb);
        }
    }
  }
  __syncthreads();   // B4

  // ---------- LN1 + residual: y = LN(o)*g+b + xw, in place on Y; 8 lanes/row ----------
  {
    int t = tid >> 3, oc = tid & 7;
    float v[32];
    float s1 = 0.f;
    #pragma unroll
    for (int b2 = 0; b2 < 4; ++b2) {
      s16x8 vb = *(const s16x8*)(sm + L_Y + t * 512 + swzb(t, oc * 64 + b2 * 16));
      #pragma unroll
      for (int e = 0; e < 8; ++e) { float fv = bf2f((unsigned short)vb[e]); v[b2*8+e] = fv; s1 += fv; }
    }
    s1 += __shfl_xor(s1, 1);
    s1 += __shfl_xor(s1, 2);
    s1 += __shfl_xor(s1, 4);
    float mu = s1 * (1.f / 256.f);
    float s2 = 0.f;
    #pragma unroll
    for (int e = 0; e < 32; ++e) { float d = v[e] - mu; s2 += d * d; }
    s2 += __shfl_xor(s2, 1);
    s2 += __shfl_xor(s2, 2);
    s2 += __shfl_xor(s2, 4);
    float rs = rsqrtf(s2 * (1.f / 256.f) + 1e-5f);
    #pragma unroll
    for (int b2 = 0; b2 < 4; ++b2) {
      s16x8 xb = *(const s16x8*)(sm + L_XW + t * 512 + swzb(t, oc * 64 + b2 * 16));
      s16x8 yb;
      #pragma unroll
      for (int e = 0; e < 8; ++e) {
        int c = oc * 32 + b2 * 8 + e;
        float yv = (v[b2*8+e] - mu) * rs * ln1w[c] + ln1b[c] + bf2f((unsigned short)xb[e]);
        yb[e] = (short)f2bf(yv);
      }
      *(s16x8*)(sm + L_Y + t * 512 + swzb(t, oc * 64 + b2 * 16)) = yb;
    }
  }
  __syncthreads();   // B5: Y final; XW dead

  // ---------- MLP fc1: 4 chunks barrier-free; gelu packed-b32 (h-perm baked in fc2w) ----------
  {
    const int Hoff[4] = {L_H0, L_H1, L_H2, L_H3};
    #pragma unroll 1
    for (int cc = 0; cc < 4; ++cc) {
      char* HB = sm + Hoff[cc];
      f32x4 acc1[2][4];
      #pragma unroll
      for (int a = 0; a < 2; ++a)
        #pragma unroll
        for (int b = 0; b < 4; ++b) acc1[a][b] = f32x4{0.f,0.f,0.f,0.f};
      for (int k0 = 0; k0 < 256; k0 += 32) {
        s16x8 af[4];
        #pragma unroll
        for (int mt = 0; mt < 4; ++mt) {
          int row = mt * 16 + c16;
          af[mt] = *(const s16x8*)(sm + L_Y + row * 512 + swzb(row, (k0 + g * 8) * 2));
        }
        #pragma unroll
        for (int t2 = 0; t2 < 2; ++t2) {
          int gt = cc * 16 + 2*w + t2;
          s16x8 bfr = *(const s16x8*)(fc1w + ((gt * 32 + (k0 >> 3) + g) * 16 + c16) * 8);
          #pragma unroll
          for (int mt = 0; mt < 4; ++mt)
            acc1[t2][mt] = __builtin_amdgcn_mfma_f32_16x16x32_bf16(af[mt], bfr, acc1[t2][mt], 0, 0, 0);
        }
      }
      float b1v0 = fc1b[cc * 256 + 32 * w + c16];
      float b1v1 = fc1b[cc * 256 + 32 * w + 16 + c16];
      #pragma unroll
      for (int mt = 0; mt < 4; ++mt)
        #pragma unroll
        for (int r = 0; r < 4; ++r) {
          int i = mt * 16 + 4 * g + r;
          float u0 = acc1[0][mt][r] + b1v0;
          float u1 = acc1[1][mt][r] + b1v1;
          float z0 = 0.7978845608f * u0 * (1.f + 0.044715f * u0 * u0);
          float z1 = 0.7978845608f * u1 * (1.f + 0.044715f * u1 * u1);
          float e0 = __expf(2.f * z0), e1 = __expf(2.f * z1);
          float g0 = u0 * e0 / (e0 + 1.f), g1 = u1 * e1 / (e1 + 1.f);
          unsigned u = (unsigned)f2bf(g0) | ((unsigned)f2bf(g1) << 16);
          *(unsigned*)(HB + i * 512 + swzb(i, w * 64 + c16 * 4)) = u;
        }
    }
  }
  __syncthreads();   // B6: all H complete

  // ---------- MLP fc2: barrier-free pass over K=1024 (perm baked in fc2w) ----------
  f32x4 acc2[2][4];
  #pragma unroll
  for (int a = 0; a < 2; ++a)
    #pragma unroll
    for (int b = 0; b < 4; ++b) acc2[a][b] = f32x4{0.f,0.f,0.f,0.f};
  {
    const int Hoff[4] = {L_H0, L_H1, L_H2, L_H3};
    #pragma unroll 1
    for (int cc = 0; cc < 4; ++cc) {
      const char* HB = sm + Hoff[cc];
      for (int k0 = 0; k0 < 256; k0 += 32) {
        s16x8 af[4];
        #pragma unroll
        for (int mt = 0; mt < 4; ++mt) {
          int row = mt * 16 + c16;
          af[mt] = *(const s16x8*)(HB + row * 512 + swzb(row, (k0 + g * 8) * 2));
        }
        #pragma unroll
        for (int t2 = 0; t2 < 2; ++t2) {
          int kg = cc * 32 + (k0 >> 3) + g;
          s16x8 bfr = *(const s16x8*)(fc2w + (((2*w + t2) * 128 + kg) * 16 + c16) * 8);
          #pragma unroll
          for (int mt = 0; mt < 4; ++mt)
            acc2[t2][mt] = __builtin_amdgcn_mfma_f32_16x16x32_bf16(af[mt], bfr, acc2[t2][mt], 0, 0, 0);
        }
      }
    }
  }
  __syncthreads();   // B7: fc2 H reads done (MB overwrites H1)

  // ---------- fc2 epilogue -> MB ----------
  #pragma unroll
  for (int t2 = 0; t2 < 2; ++t2) {
    int col = (2*w + t2) * 16 + c16;
    float b2v = fc2b[col];
    #pragma unroll
    for (int mt = 0; mt < 4; ++mt)
      #pragma unroll
      for (int r = 0; r < 4; ++r) {
        int i = mt * 16 + 4 * g + r;
        *(unsigned short*)(sm + L_MB + i * 512 + swzb(i, col * 2)) = f2bf(acc2[t2][mt][r] + b2v);
      }
  }
  __syncthreads();   // B8

  // ---------- LN2 + residual; direct bf16 store to sout ----------
  {
    int t2 = tid >> 3, oc = tid & 7;
    float v[32];
    float s1 = 0.f;
    #pragma unroll
    for (int b2 = 0; b2 < 4; ++b2) {
      s16x8 vb = *(const s16x8*)(sm + L_MB + t2 * 512 + swzb(t2, oc * 64 + b2 * 16));
      #pragma unroll
      for (int e = 0; e < 8; ++e) { float fv = bf2f((unsigned short)vb[e]); v[b2*8+e] = fv; s1 += fv; }
    }
    s1 += __shfl_xor(s1, 1);
    s1 += __shfl_xor(s1, 2);
    s1 += __shfl_xor(s1, 4);
    float mu = s1 * (1.f / 256.f);
    float s2 = 0.f;
    #pragma unroll
    for (int e = 0; e < 32; ++e) { float d = v[e] - mu; s2 += d * d; }
    s2 += __shfl_xor(s2, 1);
    s2 += __shfl_xor(s2, 2);
    s2 += __shfl_xor(s2, 4);
    float rs = rsqrtf(s2 * (1.f / 256.f) + 1e-5f);
    int rp = (wi * 8 + (t2 >> 3) + 4) & 255;
    int cp = (wj * 8 + (t2 & 7) + 4) & 255;
    size_t pix = (size_t)bb * 65536 + rp * 256 + cp;
    unsigned short* so = sout + pix * 256 + oc * 32;
    #pragma unroll
    for (int b2 = 0; b2 < 4; ++b2) {
      s16x8 yb = *(const s16x8*)(sm + L_Y + t2 * 512 + swzb(t2, oc * 64 + b2 * 16));
      s16x8 pk;
      #pragma unroll
      for (int e = 0; e < 8; ++e) {
        int c = oc * 32 + b2 * 8 + e;
        float yv = (v[b2*8+e] - mu) * rs * ln2w[c] + ln2b[c] + bf2f((unsigned short)yb[e]);
        pk[e] = (short)f2bf(yv);
      }
      *(s16x8*)(so + b2 * 8) = pk;
    }
  }
}

extern "C" void kernel_launch(void* const* d_in, const int* in_sizes, int n_in,
                              void* d_out, int out_size, void* d_ws, size_t ws_size,
                              hipStream_t stream) {
  const float* x      = (const float*)d_in[0];
  const float* qkv_w  = (const float*)d_in[1];
  const float* ls     = (const float*)d_in[2];
  const float* proj_w = (const float*)d_in[3];
  const float* proj_b = (const float*)d_in[4];
  const float* ln1w   = (const float*)d_in[5];
  const float* ln1b   = (const float*)d_in[6];
  const float* fc1_w  = (const float*)d_in[7];
  const float* fc1b   = (const float*)d_in[8];
  const float* fc2_w  = (const float*)d_in[9];
  const float* fc2b   = (const float*)d_in[10];
  const float* ln2w   = (const float*)d_in[11];
  const float* ln2b   = (const float*)d_in[12];
  const float* cpb_w1 = (const float*)d_in[13];
  const float* cpb_b1 = (const float*)d_in[14];
  const float* cpb_w2 = (const float*)d_in[15];
  unsigned char* wsb = (unsigned char*)d_ws;
  float* out = (float*)d_out;

  hipFuncSetAttribute(reinterpret_cast<const void*>(swin_block_kernel),
                      hipFuncAttributeMaxDynamicSharedMemorySize, SMEM_BYTES);

  prep_kernel<<<11265, 256, 0, stream>>>(qkv_w, proj_w, fc1_w, fc2_w,
                                         cpb_w1, cpb_b1, cpb_w2, x, ls, wsb);
  swin_block_kernel<<<2048, 512, SMEM_BYTES, stream>>>(
      ls, proj_b, ln1w, ln1b, fc1b, fc2b, ln2w, ln2b, wsb);
  transpose_out_kernel<<<8192, 256, 0, stream>>>(wsb, out);
}

// Round 10
// 481.584 us; speedup vs baseline: 4.3830x; 1.1088x over previous
//
#include <hip/hip_runtime.h>
#include <hip/hip_bf16.h>

typedef __attribute__((ext_vector_type(4))) float f32x4;
typedef __attribute__((ext_vector_type(8))) short s16x8;
typedef __attribute__((ext_vector_type(4))) unsigned short u16x4;

// ---- LDS layout (byte offsets), total 163840 B (160 KiB, 1 block/CU) ----
#define L_XW   0        // bf16 [64][256] swzb rows 512B (dead after LN1 -> H0)
#define L_SLAB 32768    // per head h at 32768+h*12288:
                        //   QK [64 tokens][128B]: q-packed bytes 0..63 | k-packed 64..127
                        //   P~ [64][128B] overwrites QK after S reads (same-wave order)
                        //   O  packed into P rows bytes 0..63 after PV reads
                        //   VT [32 d][128B] at +8192 (j-permuted)
#define L_NQ   131072   // f32 [8][64]: log2e*lsc/|q_i|   (dead after attention -> H3)
#define L_NK   133120   // f32 [8][64]: 1/|k_j|
#define L_Y    32768    // bf16 [64][512B] swzb (over slabs h0..h2 after proj barrier)
#define L_H0   0
#define L_H1   65536
#define L_H2   98304
#define L_H3   131072
#define L_MB   65536    // fc2 out (over H1, after fc2-read barrier)
#define SMEM_BYTES 163840

// ---- workspace layout (byte offsets) ----
#define WSO_BIAS   0          // f32 [8][64][16][4] (h,i,c16,nt): log2e*(bias - scale_h - 16)
#define WSO_QKVW   131072     // bf16 [48][32][16][8]       393216 B
#define WSO_PROJW  524288     // bf16 [16][32][16][8]  (K d-permuted per 32-group)
#define WSO_FC1W   655360     // bf16 [64][32][16][8]       524288 B
#define WSO_FC2W   1179648    // bf16 [16][128][16][8] (K d-permuted per 32-group)
#define WSO_SIN    1703936ULL // bf16 [2][65536][256]       67108864 B
#define WSO_SOUT   68812800ULL// bf16 [2][65536][256]       67108864 B

#define LOG2E 1.4426950408f

__device__ __forceinline__ unsigned short f2bf(float f) {
  __hip_bfloat16 h = __float2bfloat16(f);
  return __builtin_bit_cast(unsigned short, h);
}
__device__ __forceinline__ float bf2f(unsigned short b) {
  union { unsigned u; float f; } v; v.u = ((unsigned)b) << 16;
  return v.f;
}
__device__ __forceinline__ int swzb(int row, int byteoff) {  // 128B+ rows, 8-way spread
  return byteoff ^ ((row & 7) << 4);
}

// ---------------- merged prep: weight pack + bias MLP + input transpose ----------------
__global__ __launch_bounds__(256)
void prep_kernel(const float* __restrict__ qkv_w,
                 const float* __restrict__ proj_w,
                 const float* __restrict__ fc1_w,
                 const float* __restrict__ fc2_w,
                 const float* __restrict__ cpb_w1,
                 const float* __restrict__ cpb_b1,
                 const float* __restrict__ cpb_w2,
                 const float* __restrict__ x,
                 const float* __restrict__ ls,
                 unsigned char* __restrict__ wsb) {
  __shared__ float tile[64][66];
  const int bid = blockIdx.x;
  const int tid = threadIdx.x;

  if (bid < 3072) {
    // ---- weight pack to MFMA fragment layout (proj/fc2: K d-perm per 32-group) ----
    int e = bid * 256 + tid;
    const float* src; unsigned short* dst; int K, N; int eo; bool perm;
    if (e < 196608)       { eo = e;          src = qkv_w;  dst = (unsigned short*)(wsb + WSO_QKVW);  K = 256;  N = 768;  perm = false; }
    else if (e < 262144)  { eo = e - 196608; src = proj_w; dst = (unsigned short*)(wsb + WSO_PROJW); K = 256;  N = 256;  perm = true; }
    else if (e < 524288)  { eo = e - 262144; src = fc1_w;  dst = (unsigned short*)(wsb + WSO_FC1W);  K = 256;  N = 1024; perm = false; }
    else                  { eo = e - 524288; src = fc2_w;  dst = (unsigned short*)(wsb + WSO_FC2W);  K = 1024; N = 256;  perm = true; }
    int j = eo & 7, c = (eo >> 3) & 15, rest = eo >> 7;
    int Kg = K >> 3;
    int kg = rest % Kg, nt = rest / Kg;
    int s = kg * 8 + j;
    if (perm) s = (s & ~31) | ((s & 1) << 4) | ((s & 31) >> 1);   // slot -> original d
    dst[eo] = f2bf(src[s * N + nt * 16 + c]);
  } else if (bid == 3072) {
    // ---- relative-position-bias via CPB MLP; log2e*(bias - scale - 16) baked ----
    float (*bt)[8] = (float(*)[8])&tile[0][0];
    for (int t = tid; t < 225; t += 256) {
      int a = t / 15, b = t % 15;
      float r0 = (float)(a - 7) * (8.0f / 7.0f);
      float r1 = (float)(b - 7) * (8.0f / 7.0f);
      float f0 = (r0 >= 0.f ? 1.f : -1.f) * log2f(fabsf(r0) + 1.f) * (1.f / 3.f);
      float f1 = (r1 >= 0.f ? 1.f : -1.f) * log2f(fabsf(r1) + 1.f) * (1.f / 3.f);
      float acc[8] = {0.f,0.f,0.f,0.f,0.f,0.f,0.f,0.f};
      for (int k = 0; k < 512; ++k) {
        float hv = f0 * cpb_w1[k] + f1 * cpb_w1[512 + k] + cpb_b1[k];
        hv = fmaxf(hv, 0.f);
        #pragma unroll
        for (int h = 0; h < 8; ++h) acc[h] += hv * cpb_w2[k * 8 + h];
      }
      #pragma unroll
      for (int h = 0; h < 8; ++h) bt[t][h] = acc[h];
    }
    __syncthreads();
    float* biasp = (float*)(wsb + WSO_BIAS);
    for (int e = tid; e < 32768; e += 256) {
      int nn = e & 3, cc = (e >> 2) & 15, i = (e >> 6) & 63, h = e >> 12;
      int j = nn * 16 + cc;
      int dr = (i >> 3) - (j >> 3) + 7, dc = (i & 7) - (j & 7) + 7;
      float v = bt[dr * 15 + dc][h];
      float scale = __expf(fminf(ls[h], 4.6051702f));
      biasp[e] = LOG2E * (16.f / (1.f + expf(-v)) - (scale + 16.f));  // logit bound <= 0 in log2 domain
    }
  } else {
    // ---- x[b][c][p] f32 -> sin[b][p][c] bf16 (tiled transpose) ----
    int b2 = bid - 3073;
    int pb = b2 & 1023;
    int cg = (b2 >> 10) & 3;
    int b  = b2 >> 12;
    int p0 = pb * 64, c0 = cg * 64;
    unsigned short* sg = (unsigned short*)(wsb + WSO_SIN);

    int pi = tid & 63, cq = tid >> 6;
    for (int r = 0; r < 16; ++r) {
      int c = cq * 16 + r;
      tile[pi][c] = x[((size_t)(b * 256 + c0 + c)) * 65536 + p0 + pi];
    }
    __syncthreads();
    int po = tid >> 2, co = tid & 3;
    s16x8 pk0, pk1;
    #pragma unroll
    for (int j = 0; j < 8; ++j) {
      pk0[j] = (short)f2bf(tile[po][co * 16 + j]);
      pk1[j] = (short)f2bf(tile[po][co * 16 + 8 + j]);
    }
    unsigned short* dp = sg + ((size_t)b * 65536 + p0 + po) * 256 + c0 + co * 16;
    *(s16x8*)(dp) = pk0;
    *(s16x8*)(dp + 8) = pk1;
  }
}

// ---------------- pass B: sout[b][p][c] bf16 -> out[b][c][p] f32 (tiled transpose) ----------------
__global__ __launch_bounds__(256)
void transpose_out_kernel(const unsigned char* __restrict__ wsb, float* __restrict__ out) {
  __shared__ float tile[64][65];
  int pb = blockIdx.x & 1023;
  int cg = (blockIdx.x >> 10) & 3;
  int b  = blockIdx.x >> 12;
  int p0 = pb * 64, c0 = cg * 64;
  int tid = threadIdx.x;
  const unsigned short* sg = (const unsigned short*)(wsb + WSO_SOUT);

  int pi = tid >> 2, cq = tid & 3;
  const unsigned short* rp = sg + ((size_t)b * 65536 + p0 + pi) * 256 + c0 + cq * 16;
  s16x8 a0 = *(const s16x8*)(rp);
  s16x8 a1 = *(const s16x8*)(rp + 8);
  #pragma unroll
  for (int j = 0; j < 8; ++j) {
    tile[pi][cq * 16 + j]     = bf2f((unsigned short)a0[j]);
    tile[pi][cq * 16 + 8 + j] = bf2f((unsigned short)a1[j]);
  }
  __syncthreads();
  int ci = tid >> 6, pi2 = tid & 63;
  for (int r = 0; r < 16; ++r) {
    int c = ci * 16 + r;
    out[((size_t)(b * 256 + c0 + c)) * 65536 + p0 + pi2] = tile[pi2][c];
  }
}

// ---------------- main fused per-window kernel: 512 threads / 8 waves, wave=head ----------------
__global__ __launch_bounds__(512, 2)
void swin_block_kernel(const float* __restrict__ ls,
                       const float* __restrict__ proj_b,
                       const float* __restrict__ ln1w, const float* __restrict__ ln1b,
                       const float* __restrict__ fc1b,
                       const float* __restrict__ fc2b,
                       const float* __restrict__ ln2w, const float* __restrict__ ln2b,
                       unsigned char* __restrict__ wsb) {
  extern __shared__ char sm[];
  const int tid = threadIdx.x;
  const int w = tid >> 6;       // wave id = head id in attention
  const int lane = tid & 63;
  const int g = lane >> 4;
  const int c16 = lane & 15;

  const int blk = blockIdx.x;
  const int bb = blk >> 10;
  const int widx = blk & 1023;
  const int wi = widx >> 5, wj = widx & 31;

  const f32x4* biasv = (const f32x4*)(wsb + WSO_BIAS);
  const unsigned short* qkvw = (const unsigned short*)(wsb + WSO_QKVW);
  const unsigned short* projw = (const unsigned short*)(wsb + WSO_PROJW);
  const unsigned short* fc1w = (const unsigned short*)(wsb + WSO_FC1W);
  const unsigned short* fc2w = (const unsigned short*)(wsb + WSO_FC2W);
  const unsigned short* sin_ = (const unsigned short*)(wsb + WSO_SIN);
  unsigned short* sout = (unsigned short*)(wsb + WSO_SOUT);

  // ---------- Phase 1: copy window from sin -> XW bf16 swz ----------
  #pragma unroll
  for (int it = 0; it < 4; ++it) {
    int u = tid + it * 512;
    int t = u >> 5, cu = u & 31;
    int rp = (wi * 8 + (t >> 3) + 4) & 255;
    int cp = (wj * 8 + (t & 7) + 4) & 255;
    size_t pix = (size_t)bb * 65536 + rp * 256 + cp;
    s16x8 v = *(const s16x8*)(sin_ + pix * 256 + cu * 8);
    *(s16x8*)(sm + L_XW + t * 512 + swzb(t, cu * 16)) = v;
  }
  __syncthreads();   // B1

  char* const QB = sm + L_SLAB + w * 12288;

  // ---------- Phase Q: qkv GEMM, wave w computes head w ----------
  {
    int tiles[6] = {2*w, 2*w+1, 16+2*w, 17+2*w, 32+2*w, 33+2*w};
    f32x4 acc[6][4];
    #pragma unroll
    for (int a = 0; a < 6; ++a)
      #pragma unroll
      for (int b = 0; b < 4; ++b) acc[a][b] = f32x4{0.f,0.f,0.f,0.f};
    #pragma unroll 2
    for (int k0 = 0; k0 < 256; k0 += 32) {
      s16x8 af[4];
      #pragma unroll
      for (int mt = 0; mt < 4; ++mt) {
        int row = mt * 16 + c16;
        af[mt] = *(const s16x8*)(sm + L_XW + row * 512 + swzb(row, (k0 + g * 8) * 2));
      }
      #pragma unroll
      for (int ct = 0; ct < 6; ++ct) {
        s16x8 bfr = *(const s16x8*)(qkvw + ((tiles[ct] * 32 + (k0 >> 3) + g) * 16 + c16) * 8);
        #pragma unroll
        for (int mt = 0; mt < 4; ++mt)
          acc[ct][mt] = __builtin_amdgcn_mfma_f32_16x16x32_bf16(af[mt], bfr, acc[ct][mt], 0, 0, 0);
      }
    }
    // epilogue: q,k packed-b32 (d' = 2*(d&15)+(d>>4)); v packed-b64 (4 mt -> 4 consecutive jp)
    #pragma unroll
    for (int mt = 0; mt < 4; ++mt)
      #pragma unroll
      for (int r = 0; r < 4; ++r) {
        int i = mt * 16 + 4 * g + r;
        unsigned uq = (unsigned)f2bf(acc[0][mt][r]) | ((unsigned)f2bf(acc[1][mt][r]) << 16);
        unsigned uk = (unsigned)f2bf(acc[2][mt][r]) | ((unsigned)f2bf(acc[3][mt][r]) << 16);
        *(unsigned*)(QB + i * 128 + swzb(i, c16 * 4)) = uq;
        *(unsigned*)(QB + i * 128 + swzb(i, 64 + c16 * 4)) = uk;
      }
    #pragma unroll
    for (int dt = 0; dt < 2; ++dt)
      #pragma unroll
      for (int r = 0; r < 4; ++r) {
        int d = dt * 16 + c16;
        u16x4 vv;
        #pragma unroll
        for (int mt = 0; mt < 4; ++mt) vv[mt] = f2bf(acc[4 + dt][mt][r]);
        *(u16x4*)(QB + 8192 + d * 128 + swzb(d, 8 * (4 * g + r))) = vv;
      }
  }
  // norm pass (wave-private; DS in-order): lane reads q-row `lane` and k-row `lane`
  {
    float lsc2 = LOG2E * __expf(fminf(ls[w], 4.6051702f));
    float sq = 0.f, sk2 = 0.f;
    #pragma unroll
    for (int cc4 = 0; cc4 < 4; ++cc4) {
      s16x8 qv = *(const s16x8*)(QB + lane * 128 + swzb(lane, cc4 * 16));
      s16x8 kv = *(const s16x8*)(QB + lane * 128 + swzb(lane, 64 + cc4 * 16));
      #pragma unroll
      for (int e = 0; e < 8; ++e) {
        float a = bf2f((unsigned short)qv[e]); sq  += a * a;
        float b = bf2f((unsigned short)kv[e]); sk2 += b * b;
      }
    }
    ((float*)(sm + L_NQ))[w * 64 + lane] = lsc2 * __builtin_amdgcn_rsqf(fmaxf(sq, 1e-24f));
    ((float*)(sm + L_NK))[w * 64 + lane] = __builtin_amdgcn_rsqf(fmaxf(sk2, 1e-24f));
  }

  // ---------- Phase A: S, bounded exp2 softmax (no reductions), PV + MFMA row-sums ----------
  {
    s16x8 qf[4];
    #pragma unroll
    for (int mt = 0; mt < 4; ++mt) {
      int row = mt * 16 + c16;
      qf[mt] = *(const s16x8*)(QB + row * 128 + swzb(row, g * 16));
    }
    f32x4 S[4][4];
    #pragma unroll
    for (int nt = 0; nt < 4; ++nt) {
      int row = nt * 16 + c16;
      s16x8 kf = *(const s16x8*)(QB + row * 128 + swzb(row, 64 + g * 16));
      #pragma unroll
      for (int mt = 0; mt < 4; ++mt)
        S[mt][nt] = __builtin_amdgcn_mfma_f32_16x16x32_bf16(qf[mt], kf, f32x4{0.f,0.f,0.f,0.f}, 0, 0, 0);
    }
    const float* nqp = (const float*)(sm + L_NQ) + w * 64;
    const float* nkp = (const float*)(sm + L_NK) + w * 64;
    float rk4[4];
    #pragma unroll
    for (int nt = 0; nt < 4; ++nt) rk4[nt] = nkp[nt * 16 + c16];

    const bool edge = (wi == 31) || (wj == 31);
    if (edge) {
      int labj[4];
      #pragma unroll
      for (int nt = 0; nt < 4; ++nt) {
        int jj = nt * 16 + c16;
        int tr = jj >> 3, tc = jj & 7;
        labj[nt] = ((wi == 31) ? (tr >= 4 ? 2 : 1) : 0) * 3 + ((wj == 31) ? (tc >= 4 ? 2 : 1) : 0);
      }
      #pragma unroll
      for (int mt = 0; mt < 4; ++mt)
        #pragma unroll
        for (int r = 0; r < 4; ++r) {
          int i = mt * 16 + 4 * g + r;
          float rq = nqp[i];
          f32x4 bb4 = biasv[(w * 64 + i) * 16 + c16];
          int tr = i >> 3, tc = i & 7;
          int labi = ((wi == 31) ? (tr >= 4 ? 2 : 1) : 0) * 3 + ((wj == 31) ? (tc >= 4 ? 2 : 1) : 0);
          u16x4 pk;
          #pragma unroll
          for (int nt = 0; nt < 4; ++nt) {
            float vx = fmaf(S[mt][nt][r] * rk4[nt], rq, bb4[nt]);
            if (labi != labj[nt]) vx -= 144.2695f;
            pk[nt] = f2bf(__builtin_amdgcn_exp2f(vx));
          }
          *(u16x4*)(QB + i * 128 + swzb(i, c16 * 8)) = pk;
        }
    } else {
      #pragma unroll
      for (int mt = 0; mt < 4; ++mt)
        #pragma unroll
        for (int r = 0; r < 4; ++r) {
          int i = mt * 16 + 4 * g + r;
          float rq = nqp[i];
          f32x4 bb4 = biasv[(w * 64 + i) * 16 + c16];
          u16x4 pk;
          #pragma unroll
          for (int nt = 0; nt < 4; ++nt) {
            float vx = fmaf(S[mt][nt][r] * rk4[nt], rq, bb4[nt]);
            pk[nt] = f2bf(__builtin_amdgcn_exp2f(vx));
          }
          *(u16x4*)(QB + i * 128 + swzb(i, c16 * 8)) = pk;
        }
    }

    // PV + rowsum-via-ones: O_raw = P~ @ V ; RS = P~ @ 1 (lands in matching lanes)
    s16x8 ones;
    #pragma unroll
    for (int e = 0; e < 8; ++e) ones[e] = (short)0x3F80;
    f32x4 O[4][2], RS[4];
    #pragma unroll
    for (int a = 0; a < 4; ++a) {
      O[a][0] = f32x4{0.f,0.f,0.f,0.f};
      O[a][1] = f32x4{0.f,0.f,0.f,0.f};
      RS[a]   = f32x4{0.f,0.f,0.f,0.f};
    }
    #pragma unroll
    for (int k0 = 0; k0 < 64; k0 += 32) {
      s16x8 pf[4];
      #pragma unroll
      for (int mt = 0; mt < 4; ++mt) {
        int row = mt * 16 + c16;
        pf[mt] = *(const s16x8*)(QB + row * 128 + swzb(row, (k0 + g * 8) * 2));
      }
      #pragma unroll
      for (int nt = 0; nt < 2; ++nt) {
        int d = nt * 16 + c16;
        s16x8 vf = *(const s16x8*)(QB + 8192 + d * 128 + swzb(d, (k0 + g * 8) * 2));
        #pragma unroll
        for (int mt = 0; mt < 4; ++mt)
          O[mt][nt] = __builtin_amdgcn_mfma_f32_16x16x32_bf16(pf[mt], vf, O[mt][nt], 0, 0, 0);
      }
      #pragma unroll
      for (int mt = 0; mt < 4; ++mt)
        RS[mt] = __builtin_amdgcn_mfma_f32_16x16x32_bf16(pf[mt], ones, RS[mt], 0, 0, 0);
    }
    // normalize + packed O store into P rows bytes 0..63 (d' pairing; P reads done)
    #pragma unroll
    for (int mt = 0; mt < 4; ++mt)
      #pragma unroll
      for (int r = 0; r < 4; ++r) {
        float inv = __builtin_amdgcn_rcpf(fmaxf(RS[mt][r], 1e-35f));
        int i = mt * 16 + 4 * g + r;
        unsigned u = (unsigned)f2bf(O[mt][0][r] * inv) | ((unsigned)f2bf(O[mt][1][r] * inv) << 16);
        *(unsigned*)(QB + i * 128 + swzb(i, c16 * 4)) = u;
      }
  }
  __syncthreads();   // B2: all heads' O complete

  // ---------- Phase P: proj (K = 8 heads x 32, d-perm baked in projw) ----------
  {
    f32x4 aP[2][4];
    #pragma unroll
    for (int a = 0; a < 2; ++a)
      #pragma unroll
      for (int b = 0; b < 4; ++b) aP[a][b] = f32x4{0.f,0.f,0.f,0.f};
    #pragma unroll 2
    for (int k0 = 0; k0 < 256; k0 += 32) {
      int hk = k0 >> 5;
      const char* OBk = sm + L_SLAB + hk * 12288;
      s16x8 af[4];
      #pragma unroll
      for (int mt = 0; mt < 4; ++mt) {
        int row = mt * 16 + c16;
        af[mt] = *(const s16x8*)(OBk + row * 128 + swzb(row, g * 16));
      }
      #pragma unroll
      for (int t2 = 0; t2 < 2; ++t2) {
        s16x8 bfr = *(const s16x8*)(projw + (((2*w + t2) * 32 + 4*hk + g) * 16 + c16) * 8);
        #pragma unroll
        for (int mt = 0; mt < 4; ++mt)
          aP[t2][mt] = __builtin_amdgcn_mfma_f32_16x16x32_bf16(af[mt], bfr, aP[t2][mt], 0, 0, 0);
      }
    }
    __syncthreads();   // B3: O reads done before Y (aliased region) writes
    #pragma unroll
    for (int t2 = 0; t2 < 2; ++t2) {
      int col = (2*w + t2) * 16 + c16;
      float pb = proj_b[col];
      #pragma unroll
      for (int mt = 0; mt < 4; ++mt)
        #pragma unroll
        for (int r = 0; r < 4; ++r) {
          int i = mt * 16 + 4 * g + r;
          *(unsigned short*)(sm + L_Y + i * 512 + swzb(i, col * 2)) = f2bf(aP[t2][mt][r] + pb);
        }
    }
  }
  __syncthreads();   // B4

  // ---------- LN1 + residual: y = LN(o)*g+b + xw, in place on Y; 8 lanes/row ----------
  {
    int t = tid >> 3, oc = tid & 7;
    float v[32];
    float s1 = 0.f;
    #pragma unroll
    for (int b2 = 0; b2 < 4; ++b2) {
      s16x8 vb = *(const s16x8*)(sm + L_Y + t * 512 + swzb(t, oc * 64 + b2 * 16));
      #pragma unroll
      for (int e = 0; e < 8; ++e) { float fv = bf2f((unsigned short)vb[e]); v[b2*8+e] = fv; s1 += fv; }
    }
    s1 += __shfl_xor(s1, 1);
    s1 += __shfl_xor(s1, 2);
    s1 += __shfl_xor(s1, 4);
    float mu = s1 * (1.f / 256.f);
    float s2 = 0.f;
    #pragma unroll
    for (int e = 0; e < 32; ++e) { float d = v[e] - mu; s2 += d * d; }
    s2 += __shfl_xor(s2, 1);
    s2 += __shfl_xor(s2, 2);
    s2 += __shfl_xor(s2, 4);
    float rs = __builtin_amdgcn_rsqf(s2 * (1.f / 256.f) + 1e-5f);
    #pragma unroll
    for (int b2 = 0; b2 < 4; ++b2) {
      s16x8 xb = *(const s16x8*)(sm + L_XW + t * 512 + swzb(t, oc * 64 + b2 * 16));
      s16x8 yb;
      #pragma unroll
      for (int e = 0; e < 8; ++e) {
        int c = oc * 32 + b2 * 8 + e;
        float yv = (v[b2*8+e] - mu) * rs * ln1w[c] + ln1b[c] + bf2f((unsigned short)xb[e]);
        yb[e] = (short)f2bf(yv);
      }
      *(s16x8*)(sm + L_Y + t * 512 + swzb(t, oc * 64 + b2 * 16)) = yb;
    }
  }
  __syncthreads();   // B5: Y final; XW dead

  // ---------- MLP fc1: cc-paired K-sweeps, barrier-free; exp2 gelu + rcp ----------
  {
    const int Hoff[4] = {L_H0, L_H1, L_H2, L_H3};
    #pragma unroll 1
    for (int cp = 0; cp < 2; ++cp) {
      f32x4 acc1[2][2][4];
      #pragma unroll
      for (int a = 0; a < 2; ++a)
        #pragma unroll
        for (int b = 0; b < 2; ++b)
          #pragma unroll
          for (int m = 0; m < 4; ++m) acc1[a][b][m] = f32x4{0.f,0.f,0.f,0.f};
      for (int k0 = 0; k0 < 256; k0 += 32) {
        s16x8 af[4];
        #pragma unroll
        for (int mt = 0; mt < 4; ++mt) {
          int row = mt * 16 + c16;
          af[mt] = *(const s16x8*)(sm + L_Y + row * 512 + swzb(row, (k0 + g * 8) * 2));
        }
        #pragma unroll
        for (int cc2 = 0; cc2 < 2; ++cc2) {
          int cc = cp * 2 + cc2;
          #pragma unroll
          for (int t2 = 0; t2 < 2; ++t2) {
            int gt = cc * 16 + 2*w + t2;
            s16x8 bfr = *(const s16x8*)(fc1w + ((gt * 32 + (k0 >> 3) + g) * 16 + c16) * 8);
            #pragma unroll
            for (int mt = 0; mt < 4; ++mt)
              acc1[cc2][t2][mt] = __builtin_amdgcn_mfma_f32_16x16x32_bf16(af[mt], bfr, acc1[cc2][t2][mt], 0, 0, 0);
          }
        }
      }
      #pragma unroll
      for (int cc2 = 0; cc2 < 2; ++cc2) {
        int cc = cp * 2 + cc2;
        char* HB = sm + Hoff[cc];
        float b1v0 = fc1b[cc * 256 + 32 * w + c16];
        float b1v1 = fc1b[cc * 256 + 32 * w + 16 + c16];
        #pragma unroll
        for (int mt = 0; mt < 4; ++mt)
          #pragma unroll
          for (int r = 0; r < 4; ++r) {
            int i = mt * 16 + 4 * g + r;
            float u0 = acc1[cc2][0][mt][r] + b1v0;
            float u1 = acc1[cc2][1][mt][r] + b1v1;
            // gelu tanh-form via sigmoid in exp2 domain: ge = u * e/(e+1), e = 2^(u*(c0 + c1*u^2))
            float z0 = fminf(u0 * fmaf(0.102943f, u0 * u0, 2.3021944f), 126.f);
            float z1 = fminf(u1 * fmaf(0.102943f, u1 * u1, 2.3021944f), 126.f);
            float e0 = __builtin_amdgcn_exp2f(z0);
            float e1 = __builtin_amdgcn_exp2f(z1);
            float g0 = u0 * e0 * __builtin_amdgcn_rcpf(e0 + 1.f);
            float g1 = u1 * e1 * __builtin_amdgcn_rcpf(e1 + 1.f);
            unsigned u = (unsigned)f2bf(g0) | ((unsigned)f2bf(g1) << 16);
            *(unsigned*)(HB + i * 512 + swzb(i, w * 64 + c16 * 4)) = u;
          }
      }
    }
  }
  __syncthreads();   // B6: all H complete

  // ---------- MLP fc2: barrier-free pass over K=1024 (perm baked in fc2w) ----------
  f32x4 acc2[2][4];
  #pragma unroll
  for (int a = 0; a < 2; ++a)
    #pragma unroll
    for (int b = 0; b < 4; ++b) acc2[a][b] = f32x4{0.f,0.f,0.f,0.f};
  {
    const int Hoff[4] = {L_H0, L_H1, L_H2, L_H3};
    #pragma unroll 1
    for (int cc = 0; cc < 4; ++cc) {
      const char* HB = sm + Hoff[cc];
      for (int k0 = 0; k0 < 256; k0 += 32) {
        s16x8 af[4];
        #pragma unroll
        for (int mt = 0; mt < 4; ++mt) {
          int row = mt * 16 + c16;
          af[mt] = *(const s16x8*)(HB + row * 512 + swzb(row, (k0 + g * 8) * 2));
        }
        #pragma unroll
        for (int t2 = 0; t2 < 2; ++t2) {
          int kg = cc * 32 + (k0 >> 3) + g;
          s16x8 bfr = *(const s16x8*)(fc2w + (((2*w + t2) * 128 + kg) * 16 + c16) * 8);
          #pragma unroll
          for (int mt = 0; mt < 4; ++mt)
            acc2[t2][mt] = __builtin_amdgcn_mfma_f32_16x16x32_bf16(af[mt], bfr, acc2[t2][mt], 0, 0, 0);
        }
      }
    }
  }
  __syncthreads();   // B7: fc2 H reads done (MB overwrites H1)

  // ---------- fc2 epilogue -> MB ----------
  #pragma unroll
  for (int t2 = 0; t2 < 2; ++t2) {
    int col = (2*w + t2) * 16 + c16;
    float b2v = fc2b[col];
    #pragma unroll
    for (int mt = 0; mt < 4; ++mt)
      #pragma unroll
      for (int r = 0; r < 4; ++r) {
        int i = mt * 16 + 4 * g + r;
        *(unsigned short*)(sm + L_MB + i * 512 + swzb(i, col * 2)) = f2bf(acc2[t2][mt][r] + b2v);
      }
  }
  __syncthreads();   // B8

  // ---------- LN2 + residual; direct bf16 store to sout ----------
  {
    int t2 = tid >> 3, oc = tid & 7;
    float v[32];
    float s1 = 0.f;
    #pragma unroll
    for (int b2 = 0; b2 < 4; ++b2) {
      s16x8 vb = *(const s16x8*)(sm + L_MB + t2 * 512 + swzb(t2, oc * 64 + b2 * 16));
      #pragma unroll
      for (int e = 0; e < 8; ++e) { float fv = bf2f((unsigned short)vb[e]); v[b2*8+e] = fv; s1 += fv; }
    }
    s1 += __shfl_xor(s1, 1);
    s1 += __shfl_xor(s1, 2);
    s1 += __shfl_xor(s1, 4);
    float mu = s1 * (1.f / 256.f);
    float s2 = 0.f;
    #pragma unroll
    for (int e = 0; e < 32; ++e) { float d = v[e] - mu; s2 += d * d; }
    s2 += __shfl_xor(s2, 1);
    s2 += __shfl_xor(s2, 2);
    s2 += __shfl_xor(s2, 4);
    float rs = __builtin_amdgcn_rsqf(s2 * (1.f / 256.f) + 1e-5f);
    int rp = (wi * 8 + (t2 >> 3) + 4) & 255;
    int cp = (wj * 8 + (t2 & 7) + 4) & 255;
    size_t pix = (size_t)bb * 65536 + rp * 256 + cp;
    unsigned short* so = sout + pix * 256 + oc * 32;
    #pragma unroll
    for (int b2 = 0; b2 < 4; ++b2) {
      s16x8 yb = *(const s16x8*)(sm + L_Y + t2 * 512 + swzb(t2, oc * 64 + b2 * 16));
      s16x8 pk;
      #pragma unroll
      for (int e = 0; e < 8; ++e) {
        int c = oc * 32 + b2 * 8 + e;
        float yv = (v[b2*8+e] - mu) * rs * ln2w[c] + ln2b[c] + bf2f((unsigned short)yb[e]);
        pk[e] = (short)f2bf(yv);
      }
      *(s16x8*)(so + b2 * 8) = pk;
    }
  }
}

extern "C" void kernel_launch(void* const* d_in, const int* in_sizes, int n_in,
                              void* d_out, int out_size, void* d_ws, size_t ws_size,
                              hipStream_t stream) {
  const float* x      = (const float*)d_in[0];
  const float* qkv_w  = (const float*)d_in[1];
  const float* ls     = (const float*)d_in[2];
  const float* proj_w = (const float*)d_in[3];
  const float* proj_b = (const float*)d_in[4];
  const float* ln1w   = (const float*)d_in[5];
  const float* ln1b   = (const float*)d_in[6];
  const float* fc1_w  = (const float*)d_in[7];
  const float* fc1b   = (const float*)d_in[8];
  const float* fc2_w  = (const float*)d_in[9];
  const float* fc2b   = (const float*)d_in[10];
  const float* ln2w   = (const float*)d_in[11];
  const float* ln2b   = (const float*)d_in[12];
  const float* cpb_w1 = (const float*)d_in[13];
  const float* cpb_b1 = (const float*)d_in[14];
  const float* cpb_w2 = (const float*)d_in[15];
  unsigned char* wsb = (unsigned char*)d_ws;
  float* out = (float*)d_out;

  hipFuncSetAttribute(reinterpret_cast<const void*>(swin_block_kernel),
                      hipFuncAttributeMaxDynamicSharedMemorySize, SMEM_BYTES);

  prep_kernel<<<11265, 256, 0, stream>>>(qkv_w, proj_w, fc1_w, fc2_w,
                                         cpb_w1, cpb_b1, cpb_w2, x, ls, wsb);
  swin_block_kernel<<<2048, 512, SMEM_BYTES, stream>>>(
      ls, proj_b, ln1w, ln1b, fc1b, fc2b, ln2w, ln2b, wsb);
  transpose_out_kernel<<<8192, 256, 0, stream>>>(wsb, out);
}

// Round 11
// 472.063 us; speedup vs baseline: 4.4714x; 1.0202x over previous
//
#include <hip/hip_runtime.h>
#include <hip/hip_bf16.h>

typedef __attribute__((ext_vector_type(4))) float f32x4;
typedef __attribute__((ext_vector_type(8))) short s16x8;
typedef __attribute__((ext_vector_type(4))) unsigned short u16x4;

// ---- LDS layout (byte offsets), total 163840 B (160 KiB, 1 block/CU) ----
#define L_XW   0        // bf16 [64][256] swzb rows 512B (dead after LN1 -> H0)
#define L_SLAB 32768    // per head h at 32768+h*12288:
                        //   QK [64 tokens][128B]: q-packed bytes 0..63 | k-packed 64..127
                        //   P~ [64][128B] overwrites QK after S reads (same-wave order)
                        //   O  packed into P rows bytes 0..63 after PV reads
                        //   VT [32 d][128B] at +8192 (j-permuted)
#define L_NQ   131072   // f32 [8][64]: log2e*lsc/|q_i|  (dead after softmax -> Y)
#define L_NK   133120   // f32 [8][64]: 1/|k_j|          (dead after softmax -> Y)
// Y lives in the TOP 32KB so it does NOT alias the O-slabs -> no barrier between
// proj MFMA (slab reads) and Y writes. NQ/NK alias Y temporally (dead before B2).
#define L_Y    131072   // bf16 [64][512B] swzb
#define L_H0   0        // H chunks in the bottom 128KB (over XW + slabs, dead after B5)
#define L_H1   32768
#define L_H2   65536
#define L_H3   98304
#define L_MB   0        // fc2 out (over H0, after fc2-read barrier)
#define SMEM_BYTES 163840

// ---- workspace layout (byte offsets) ----
#define WSO_BIAS   0          // f32 [8][64][16][4] (h,i,c16,nt): log2e*(bias - scale_h - 16)
#define WSO_QKVW   131072     // bf16 [48][32][16][8]       393216 B
#define WSO_PROJW  524288     // bf16 [16][32][16][8]  (K d-permuted per 32-group)
#define WSO_FC1W   655360     // bf16 [64][32][16][8]       524288 B
#define WSO_FC2W   1179648    // bf16 [16][128][16][8] (K d-permuted per 32-group)
#define WSO_SIN    1703936ULL // bf16 [2][65536][256]       67108864 B
#define WSO_SOUT   68812800ULL// bf16 [2][65536][256]       67108864 B

#define LOG2E 1.4426950408f

__device__ __forceinline__ unsigned short f2bf(float f) {
  __hip_bfloat16 h = __float2bfloat16(f);
  return __builtin_bit_cast(unsigned short, h);
}
__device__ __forceinline__ float bf2f(unsigned short b) {
  union { unsigned u; float f; } v; v.u = ((unsigned)b) << 16;
  return v.f;
}
__device__ __forceinline__ int swzb(int row, int byteoff) {  // 128B+ rows, 8-way spread
  return byteoff ^ ((row & 7) << 4);
}

// ---------------- merged prep: weight pack + bias MLP + input transpose ----------------
__global__ __launch_bounds__(256)
void prep_kernel(const float* __restrict__ qkv_w,
                 const float* __restrict__ proj_w,
                 const float* __restrict__ fc1_w,
                 const float* __restrict__ fc2_w,
                 const float* __restrict__ cpb_w1,
                 const float* __restrict__ cpb_b1,
                 const float* __restrict__ cpb_w2,
                 const float* __restrict__ x,
                 const float* __restrict__ ls,
                 unsigned char* __restrict__ wsb) {
  __shared__ float tile[64][66];
  const int bid = blockIdx.x;
  const int tid = threadIdx.x;

  if (bid < 3072) {
    // ---- weight pack to MFMA fragment layout (proj/fc2: K d-perm per 32-group) ----
    int e = bid * 256 + tid;
    const float* src; unsigned short* dst; int K, N; int eo; bool perm;
    if (e < 196608)       { eo = e;          src = qkv_w;  dst = (unsigned short*)(wsb + WSO_QKVW);  K = 256;  N = 768;  perm = false; }
    else if (e < 262144)  { eo = e - 196608; src = proj_w; dst = (unsigned short*)(wsb + WSO_PROJW); K = 256;  N = 256;  perm = true; }
    else if (e < 524288)  { eo = e - 262144; src = fc1_w;  dst = (unsigned short*)(wsb + WSO_FC1W);  K = 256;  N = 1024; perm = false; }
    else                  { eo = e - 524288; src = fc2_w;  dst = (unsigned short*)(wsb + WSO_FC2W);  K = 1024; N = 256;  perm = true; }
    int j = eo & 7, c = (eo >> 3) & 15, rest = eo >> 7;
    int Kg = K >> 3;
    int kg = rest % Kg, nt = rest / Kg;
    int s = kg * 8 + j;
    if (perm) s = (s & ~31) | ((s & 1) << 4) | ((s & 31) >> 1);   // slot -> original d
    dst[eo] = f2bf(src[s * N + nt * 16 + c]);
  } else if (bid == 3072) {
    // ---- relative-position-bias via CPB MLP; log2e*(bias - scale - 16) baked ----
    float (*bt)[8] = (float(*)[8])&tile[0][0];
    for (int t = tid; t < 225; t += 256) {
      int a = t / 15, b = t % 15;
      float r0 = (float)(a - 7) * (8.0f / 7.0f);
      float r1 = (float)(b - 7) * (8.0f / 7.0f);
      float f0 = (r0 >= 0.f ? 1.f : -1.f) * log2f(fabsf(r0) + 1.f) * (1.f / 3.f);
      float f1 = (r1 >= 0.f ? 1.f : -1.f) * log2f(fabsf(r1) + 1.f) * (1.f / 3.f);
      float acc[8] = {0.f,0.f,0.f,0.f,0.f,0.f,0.f,0.f};
      for (int k = 0; k < 512; ++k) {
        float hv = f0 * cpb_w1[k] + f1 * cpb_w1[512 + k] + cpb_b1[k];
        hv = fmaxf(hv, 0.f);
        #pragma unroll
        for (int h = 0; h < 8; ++h) acc[h] += hv * cpb_w2[k * 8 + h];
      }
      #pragma unroll
      for (int h = 0; h < 8; ++h) bt[t][h] = acc[h];
    }
    __syncthreads();
    float* biasp = (float*)(wsb + WSO_BIAS);
    for (int e = tid; e < 32768; e += 256) {
      int nn = e & 3, cc = (e >> 2) & 15, i = (e >> 6) & 63, h = e >> 12;
      int j = nn * 16 + cc;
      int dr = (i >> 3) - (j >> 3) + 7, dc = (i & 7) - (j & 7) + 7;
      float v = bt[dr * 15 + dc][h];
      float scale = __expf(fminf(ls[h], 4.6051702f));
      biasp[e] = LOG2E * (16.f / (1.f + expf(-v)) - (scale + 16.f));  // logit bound <= 0 in log2 domain
    }
  } else {
    // ---- x[b][c][p] f32 -> sin[b][p][c] bf16 (tiled transpose) ----
    int b2 = bid - 3073;
    int pb = b2 & 1023;
    int cg = (b2 >> 10) & 3;
    int b  = b2 >> 12;
    int p0 = pb * 64, c0 = cg * 64;
    unsigned short* sg = (unsigned short*)(wsb + WSO_SIN);

    int pi = tid & 63, cq = tid >> 6;
    for (int r = 0; r < 16; ++r) {
      int c = cq * 16 + r;
      tile[pi][c] = x[((size_t)(b * 256 + c0 + c)) * 65536 + p0 + pi];
    }
    __syncthreads();
    int po = tid >> 2, co = tid & 3;
    s16x8 pk0, pk1;
    #pragma unroll
    for (int j = 0; j < 8; ++j) {
      pk0[j] = (short)f2bf(tile[po][co * 16 + j]);
      pk1[j] = (short)f2bf(tile[po][co * 16 + 8 + j]);
    }
    unsigned short* dp = sg + ((size_t)b * 65536 + p0 + po) * 256 + c0 + co * 16;
    *(s16x8*)(dp) = pk0;
    *(s16x8*)(dp + 8) = pk1;
  }
}

// ---------------- pass B: sout[b][p][c] bf16 -> out[b][c][p] f32 (tiled transpose) ----------------
__global__ __launch_bounds__(256)
void transpose_out_kernel(const unsigned char* __restrict__ wsb, float* __restrict__ out) {
  __shared__ float tile[64][65];
  int pb = blockIdx.x & 1023;
  int cg = (blockIdx.x >> 10) & 3;
  int b  = blockIdx.x >> 12;
  int p0 = pb * 64, c0 = cg * 64;
  int tid = threadIdx.x;
  const unsigned short* sg = (const unsigned short*)(wsb + WSO_SOUT);

  int pi = tid >> 2, cq = tid & 3;
  const unsigned short* rp = sg + ((size_t)b * 65536 + p0 + pi) * 256 + c0 + cq * 16;
  s16x8 a0 = *(const s16x8*)(rp);
  s16x8 a1 = *(const s16x8*)(rp + 8);
  #pragma unroll
  for (int j = 0; j < 8; ++j) {
    tile[pi][cq * 16 + j]     = bf2f((unsigned short)a0[j]);
    tile[pi][cq * 16 + 8 + j] = bf2f((unsigned short)a1[j]);
  }
  __syncthreads();
  int ci = tid >> 6, pi2 = tid & 63;
  for (int r = 0; r < 16; ++r) {
    int c = ci * 16 + r;
    out[((size_t)(b * 256 + c0 + c)) * 65536 + p0 + pi2] = tile[pi2][c];
  }
}

// ---------------- main fused per-window kernel: 512 threads / 8 waves, wave=head ----------------
__global__ __launch_bounds__(512, 2)
void swin_block_kernel(const float* __restrict__ ls,
                       const float* __restrict__ proj_b,
                       const float* __restrict__ ln1w, const float* __restrict__ ln1b,
                       const float* __restrict__ fc1b,
                       const float* __restrict__ fc2b,
                       const float* __restrict__ ln2w, const float* __restrict__ ln2b,
                       unsigned char* __restrict__ wsb) {
  extern __shared__ char sm[];
  const int tid = threadIdx.x;
  const int w = tid >> 6;       // wave id = head id in attention
  const int lane = tid & 63;
  const int g = lane >> 4;
  const int c16 = lane & 15;

  const int blk = blockIdx.x;
  const int bb = blk >> 10;
  const int widx = blk & 1023;
  const int wi = widx >> 5, wj = widx & 31;

  const f32x4* biasv = (const f32x4*)(wsb + WSO_BIAS);
  const unsigned short* qkvw = (const unsigned short*)(wsb + WSO_QKVW);
  const unsigned short* projw = (const unsigned short*)(wsb + WSO_PROJW);
  const unsigned short* fc1w = (const unsigned short*)(wsb + WSO_FC1W);
  const unsigned short* fc2w = (const unsigned short*)(wsb + WSO_FC2W);
  const unsigned short* sin_ = (const unsigned short*)(wsb + WSO_SIN);
  unsigned short* sout = (unsigned short*)(wsb + WSO_SOUT);

  // ---------- Phase 1: copy window from sin -> XW bf16 swz ----------
  #pragma unroll
  for (int it = 0; it < 4; ++it) {
    int u = tid + it * 512;
    int t = u >> 5, cu = u & 31;
    int rp = (wi * 8 + (t >> 3) + 4) & 255;
    int cp = (wj * 8 + (t & 7) + 4) & 255;
    size_t pix = (size_t)bb * 65536 + rp * 256 + cp;
    s16x8 v = *(const s16x8*)(sin_ + pix * 256 + cu * 8);
    *(s16x8*)(sm + L_XW + t * 512 + swzb(t, cu * 16)) = v;
  }
  __syncthreads();   // B1

  char* const QB = sm + L_SLAB + w * 12288;

  // ---------- Phase Q: qkv GEMM, wave w computes head w ----------
  {
    int tiles[6] = {2*w, 2*w+1, 16+2*w, 17+2*w, 32+2*w, 33+2*w};
    f32x4 acc[6][4];
    #pragma unroll
    for (int a = 0; a < 6; ++a)
      #pragma unroll
      for (int b = 0; b < 4; ++b) acc[a][b] = f32x4{0.f,0.f,0.f,0.f};
    #pragma unroll 4
    for (int k0 = 0; k0 < 256; k0 += 32) {
      s16x8 af[4];
      #pragma unroll
      for (int mt = 0; mt < 4; ++mt) {
        int row = mt * 16 + c16;
        af[mt] = *(const s16x8*)(sm + L_XW + row * 512 + swzb(row, (k0 + g * 8) * 2));
      }
      #pragma unroll
      for (int ct = 0; ct < 6; ++ct) {
        s16x8 bfr = *(const s16x8*)(qkvw + ((tiles[ct] * 32 + (k0 >> 3) + g) * 16 + c16) * 8);
        #pragma unroll
        for (int mt = 0; mt < 4; ++mt)
          acc[ct][mt] = __builtin_amdgcn_mfma_f32_16x16x32_bf16(af[mt], bfr, acc[ct][mt], 0, 0, 0);
      }
    }
    // epilogue: q,k packed-b32 (d' = 2*(d&15)+(d>>4)); v packed-b64 (4 mt -> 4 consecutive jp)
    #pragma unroll
    for (int mt = 0; mt < 4; ++mt)
      #pragma unroll
      for (int r = 0; r < 4; ++r) {
        int i = mt * 16 + 4 * g + r;
        unsigned uq = (unsigned)f2bf(acc[0][mt][r]) | ((unsigned)f2bf(acc[1][mt][r]) << 16);
        unsigned uk = (unsigned)f2bf(acc[2][mt][r]) | ((unsigned)f2bf(acc[3][mt][r]) << 16);
        *(unsigned*)(QB + i * 128 + swzb(i, c16 * 4)) = uq;
        *(unsigned*)(QB + i * 128 + swzb(i, 64 + c16 * 4)) = uk;
      }
    #pragma unroll
    for (int dt = 0; dt < 2; ++dt)
      #pragma unroll
      for (int r = 0; r < 4; ++r) {
        int d = dt * 16 + c16;
        u16x4 vv;
        #pragma unroll
        for (int mt = 0; mt < 4; ++mt) vv[mt] = f2bf(acc[4 + dt][mt][r]);
        *(u16x4*)(QB + 8192 + d * 128 + swzb(d, 8 * (4 * g + r))) = vv;
      }
  }
  // norm pass (wave-private; DS in-order): lane reads q-row `lane` and k-row `lane`
  {
    float lsc2 = LOG2E * __expf(fminf(ls[w], 4.6051702f));
    float sq = 0.f, sk2 = 0.f;
    #pragma unroll
    for (int cc4 = 0; cc4 < 4; ++cc4) {
      s16x8 qv = *(const s16x8*)(QB + lane * 128 + swzb(lane, cc4 * 16));
      s16x8 kv = *(const s16x8*)(QB + lane * 128 + swzb(lane, 64 + cc4 * 16));
      #pragma unroll
      for (int e = 0; e < 8; ++e) {
        float a = bf2f((unsigned short)qv[e]); sq  += a * a;
        float b = bf2f((unsigned short)kv[e]); sk2 += b * b;
      }
    }
    ((float*)(sm + L_NQ))[w * 64 + lane] = lsc2 * __builtin_amdgcn_rsqf(fmaxf(sq, 1e-24f));
    ((float*)(sm + L_NK))[w * 64 + lane] = __builtin_amdgcn_rsqf(fmaxf(sk2, 1e-24f));
  }

  // ---------- Phase A: S, bounded exp2 softmax (no reductions), PV + MFMA row-sums ----------
  {
    s16x8 qf[4];
    #pragma unroll
    for (int mt = 0; mt < 4; ++mt) {
      int row = mt * 16 + c16;
      qf[mt] = *(const s16x8*)(QB + row * 128 + swzb(row, g * 16));
    }
    f32x4 S[4][4];
    #pragma unroll
    for (int nt = 0; nt < 4; ++nt) {
      int row = nt * 16 + c16;
      s16x8 kf = *(const s16x8*)(QB + row * 128 + swzb(row, 64 + g * 16));
      #pragma unroll
      for (int mt = 0; mt < 4; ++mt)
        S[mt][nt] = __builtin_amdgcn_mfma_f32_16x16x32_bf16(qf[mt], kf, f32x4{0.f,0.f,0.f,0.f}, 0, 0, 0);
    }
    const float* nqp = (const float*)(sm + L_NQ) + w * 64;
    const float* nkp = (const float*)(sm + L_NK) + w * 64;
    float rk4[4];
    #pragma unroll
    for (int nt = 0; nt < 4; ++nt) rk4[nt] = nkp[nt * 16 + c16];

    const bool edge = (wi == 31) || (wj == 31);
    if (edge) {
      int labj[4];
      #pragma unroll
      for (int nt = 0; nt < 4; ++nt) {
        int jj = nt * 16 + c16;
        int tr = jj >> 3, tc = jj & 7;
        labj[nt] = ((wi == 31) ? (tr >= 4 ? 2 : 1) : 0) * 3 + ((wj == 31) ? (tc >= 4 ? 2 : 1) : 0);
      }
      #pragma unroll
      for (int mt = 0; mt < 4; ++mt)
        #pragma unroll
        for (int r = 0; r < 4; ++r) {
          int i = mt * 16 + 4 * g + r;
          float rq = nqp[i];
          f32x4 bb4 = biasv[(w * 64 + i) * 16 + c16];
          int tr = i >> 3, tc = i & 7;
          int labi = ((wi == 31) ? (tr >= 4 ? 2 : 1) : 0) * 3 + ((wj == 31) ? (tc >= 4 ? 2 : 1) : 0);
          u16x4 pk;
          #pragma unroll
          for (int nt = 0; nt < 4; ++nt) {
            float vx = fmaf(S[mt][nt][r] * rk4[nt], rq, bb4[nt]);
            if (labi != labj[nt]) vx -= 144.2695f;
            pk[nt] = f2bf(__builtin_amdgcn_exp2f(vx));
          }
          *(u16x4*)(QB + i * 128 + swzb(i, c16 * 8)) = pk;
        }
    } else {
      #pragma unroll
      for (int mt = 0; mt < 4; ++mt)
        #pragma unroll
        for (int r = 0; r < 4; ++r) {
          int i = mt * 16 + 4 * g + r;
          float rq = nqp[i];
          f32x4 bb4 = biasv[(w * 64 + i) * 16 + c16];
          u16x4 pk;
          #pragma unroll
          for (int nt = 0; nt < 4; ++nt) {
            float vx = fmaf(S[mt][nt][r] * rk4[nt], rq, bb4[nt]);
            pk[nt] = f2bf(__builtin_amdgcn_exp2f(vx));
          }
          *(u16x4*)(QB + i * 128 + swzb(i, c16 * 8)) = pk;
        }
    }

    // PV + rowsum-via-ones: O_raw = P~ @ V ; RS = P~ @ 1 (lands in matching lanes)
    s16x8 ones;
    #pragma unroll
    for (int e = 0; e < 8; ++e) ones[e] = (short)0x3F80;
    f32x4 O[4][2], RS[4];
    #pragma unroll
    for (int a = 0; a < 4; ++a) {
      O[a][0] = f32x4{0.f,0.f,0.f,0.f};
      O[a][1] = f32x4{0.f,0.f,0.f,0.f};
      RS[a]   = f32x4{0.f,0.f,0.f,0.f};
    }
    #pragma unroll
    for (int k0 = 0; k0 < 64; k0 += 32) {
      s16x8 pf[4];
      #pragma unroll
      for (int mt = 0; mt < 4; ++mt) {
        int row = mt * 16 + c16;
        pf[mt] = *(const s16x8*)(QB + row * 128 + swzb(row, (k0 + g * 8) * 2));
      }
      #pragma unroll
      for (int nt = 0; nt < 2; ++nt) {
        int d = nt * 16 + c16;
        s16x8 vf = *(const s16x8*)(QB + 8192 + d * 128 + swzb(d, (k0 + g * 8) * 2));
        #pragma unroll
        for (int mt = 0; mt < 4; ++mt)
          O[mt][nt] = __builtin_amdgcn_mfma_f32_16x16x32_bf16(pf[mt], vf, O[mt][nt], 0, 0, 0);
      }
      #pragma unroll
      for (int mt = 0; mt < 4; ++mt)
        RS[mt] = __builtin_amdgcn_mfma_f32_16x16x32_bf16(pf[mt], ones, RS[mt], 0, 0, 0);
    }
    // normalize + packed O store into P rows bytes 0..63 (d' pairing; P reads done)
    #pragma unroll
    for (int mt = 0; mt < 4; ++mt)
      #pragma unroll
      for (int r = 0; r < 4; ++r) {
        float inv = __builtin_amdgcn_rcpf(fmaxf(RS[mt][r], 1e-35f));
        int i = mt * 16 + 4 * g + r;
        unsigned u = (unsigned)f2bf(O[mt][0][r] * inv) | ((unsigned)f2bf(O[mt][1][r] * inv) << 16);
        *(unsigned*)(QB + i * 128 + swzb(i, c16 * 4)) = u;
      }
  }
  __syncthreads();   // B2: all heads' O complete

  // ---------- Phase P: proj (K = 8 heads x 32, d-perm baked in projw) ----------
  // Y is in the top 32KB (disjoint from slabs), so no barrier between slab reads and Y writes.
  {
    f32x4 aP[2][4];
    #pragma unroll
    for (int a = 0; a < 2; ++a)
      #pragma unroll
      for (int b = 0; b < 4; ++b) aP[a][b] = f32x4{0.f,0.f,0.f,0.f};
    #pragma unroll 2
    for (int k0 = 0; k0 < 256; k0 += 32) {
      int hk = k0 >> 5;
      const char* OBk = sm + L_SLAB + hk * 12288;
      s16x8 af[4];
      #pragma unroll
      for (int mt = 0; mt < 4; ++mt) {
        int row = mt * 16 + c16;
        af[mt] = *(const s16x8*)(OBk + row * 128 + swzb(row, g * 16));
      }
      #pragma unroll
      for (int t2 = 0; t2 < 2; ++t2) {
        s16x8 bfr = *(const s16x8*)(projw + (((2*w + t2) * 32 + 4*hk + g) * 16 + c16) * 8);
        #pragma unroll
        for (int mt = 0; mt < 4; ++mt)
          aP[t2][mt] = __builtin_amdgcn_mfma_f32_16x16x32_bf16(af[mt], bfr, aP[t2][mt], 0, 0, 0);
      }
    }
    #pragma unroll
    for (int t2 = 0; t2 < 2; ++t2) {
      int col = (2*w + t2) * 16 + c16;
      float pb = proj_b[col];
      #pragma unroll
      for (int mt = 0; mt < 4; ++mt)
        #pragma unroll
        for (int r = 0; r < 4; ++r) {
          int i = mt * 16 + 4 * g + r;
          *(unsigned short*)(sm + L_Y + i * 512 + swzb(i, col * 2)) = f2bf(aP[t2][mt][r] + pb);
        }
    }
  }
  __syncthreads();   // B4 (Y complete; NQ/NK dead)

  // ---------- LN1 + residual: y = LN(o)*g+b + xw, in place on Y; 8 lanes/row ----------
  {
    int t = tid >> 3, oc = tid & 7;
    float v[32];
    float s1 = 0.f;
    #pragma unroll
    for (int b2 = 0; b2 < 4; ++b2) {
      s16x8 vb = *(const s16x8*)(sm + L_Y + t * 512 + swzb(t, oc * 64 + b2 * 16));
      #pragma unroll
      for (int e = 0; e < 8; ++e) { float fv = bf2f((unsigned short)vb[e]); v[b2*8+e] = fv; s1 += fv; }
    }
    s1 += __shfl_xor(s1, 1);
    s1 += __shfl_xor(s1, 2);
    s1 += __shfl_xor(s1, 4);
    float mu = s1 * (1.f / 256.f);
    float s2 = 0.f;
    #pragma unroll
    for (int e = 0; e < 32; ++e) { float d = v[e] - mu; s2 += d * d; }
    s2 += __shfl_xor(s2, 1);
    s2 += __shfl_xor(s2, 2);
    s2 += __shfl_xor(s2, 4);
    float rs = __builtin_amdgcn_rsqf(s2 * (1.f / 256.f) + 1e-5f);
    #pragma unroll
    for (int b2 = 0; b2 < 4; ++b2) {
      s16x8 xb = *(const s16x8*)(sm + L_XW + t * 512 + swzb(t, oc * 64 + b2 * 16));
      s16x8 yb;
      #pragma unroll
      for (int e = 0; e < 8; ++e) {
        int c = oc * 32 + b2 * 8 + e;
        float yv = (v[b2*8+e] - mu) * rs * ln1w[c] + ln1b[c] + bf2f((unsigned short)xb[e]);
        yb[e] = (short)f2bf(yv);
      }
      *(s16x8*)(sm + L_Y + t * 512 + swzb(t, oc * 64 + b2 * 16)) = yb;
    }
  }
  __syncthreads();   // B5: Y final; XW/slabs dead -> H buffers

  // ---------- MLP fc1: cc-paired K-sweeps, barrier-free; sigmoid-form gelu ----------
  {
    const int Hoff[4] = {L_H0, L_H1, L_H2, L_H3};
    #pragma unroll 1
    for (int cp = 0; cp < 2; ++cp) {
      f32x4 acc1[2][2][4];
      #pragma unroll
      for (int a = 0; a < 2; ++a)
        #pragma unroll
        for (int b = 0; b < 2; ++b)
          #pragma unroll
          for (int m = 0; m < 4; ++m) acc1[a][b][m] = f32x4{0.f,0.f,0.f,0.f};
      for (int k0 = 0; k0 < 256; k0 += 32) {
        s16x8 af[4];
        #pragma unroll
        for (int mt = 0; mt < 4; ++mt) {
          int row = mt * 16 + c16;
          af[mt] = *(const s16x8*)(sm + L_Y + row * 512 + swzb(row, (k0 + g * 8) * 2));
        }
        #pragma unroll
        for (int cc2 = 0; cc2 < 2; ++cc2) {
          int cc = cp * 2 + cc2;
          #pragma unroll
          for (int t2 = 0; t2 < 2; ++t2) {
            int gt = cc * 16 + 2*w + t2;
            s16x8 bfr = *(const s16x8*)(fc1w + ((gt * 32 + (k0 >> 3) + g) * 16 + c16) * 8);
            #pragma unroll
            for (int mt = 0; mt < 4; ++mt)
              acc1[cc2][t2][mt] = __builtin_amdgcn_mfma_f32_16x16x32_bf16(af[mt], bfr, acc1[cc2][t2][mt], 0, 0, 0);
          }
        }
      }
      #pragma unroll
      for (int cc2 = 0; cc2 < 2; ++cc2) {
        int cc = cp * 2 + cc2;
        char* HB = sm + Hoff[cc];
        float b1v0 = fc1b[cc * 256 + 32 * w + c16];
        float b1v1 = fc1b[cc * 256 + 32 * w + 16 + c16];
        #pragma unroll
        for (int mt = 0; mt < 4; ++mt)
          #pragma unroll
          for (int r = 0; r < 4; ++r) {
            int i = mt * 16 + 4 * g + r;
            float u0 = acc1[cc2][0][mt][r] + b1v0;
            float u1 = acc1[cc2][1][mt][r] + b1v1;
            // gelu ~ u * sigmoid(1.702u) = u * rcp(1 + 2^(-2.45538u)); clamp-free
            float e0 = __builtin_amdgcn_exp2f(-2.45538f * u0);
            float e1 = __builtin_amdgcn_exp2f(-2.45538f * u1);
            float g0 = u0 * __builtin_amdgcn_rcpf(1.f + e0);
            float g1 = u1 * __builtin_amdgcn_rcpf(1.f + e1);
            unsigned u = (unsigned)f2bf(g0) | ((unsigned)f2bf(g1) << 16);
            *(unsigned*)(HB + i * 512 + swzb(i, w * 64 + c16 * 4)) = u;
          }
      }
    }
  }
  __syncthreads();   // B6: all H complete

  // ---------- MLP fc2: barrier-free pass over K=1024 (perm baked in fc2w) ----------
  f32x4 acc2[2][4];
  #pragma unroll
  for (int a = 0; a < 2; ++a)
    #pragma unroll
    for (int b = 0; b < 4; ++b) acc2[a][b] = f32x4{0.f,0.f,0.f,0.f};
  {
    const int Hoff[4] = {L_H0, L_H1, L_H2, L_H3};
    #pragma unroll 1
    for (int cc = 0; cc < 4; ++cc) {
      const char* HB = sm + Hoff[cc];
      for (int k0 = 0; k0 < 256; k0 += 32) {
        s16x8 af[4];
        #pragma unroll
        for (int mt = 0; mt < 4; ++mt) {
          int row = mt * 16 + c16;
          af[mt] = *(const s16x8*)(HB + row * 512 + swzb(row, (k0 + g * 8) * 2));
        }
        #pragma unroll
        for (int t2 = 0; t2 < 2; ++t2) {
          int kg = cc * 32 + (k0 >> 3) + g;
          s16x8 bfr = *(const s16x8*)(fc2w + (((2*w + t2) * 128 + kg) * 16 + c16) * 8);
          #pragma unroll
          for (int mt = 0; mt < 4; ++mt)
            acc2[t2][mt] = __builtin_amdgcn_mfma_f32_16x16x32_bf16(af[mt], bfr, acc2[t2][mt], 0, 0, 0);
        }
      }
    }
  }
  __syncthreads();   // B7: fc2 H reads done (MB overwrites H0)

  // ---------- fc2 epilogue -> MB ----------
  #pragma unroll
  for (int t2 = 0; t2 < 2; ++t2) {
    int col = (2*w + t2) * 16 + c16;
    float b2v = fc2b[col];
    #pragma unroll
    for (int mt = 0; mt < 4; ++mt)
      #pragma unroll
      for (int r = 0; r < 4; ++r) {
        int i = mt * 16 + 4 * g + r;
        *(unsigned short*)(sm + L_MB + i * 512 + swzb(i, col * 2)) = f2bf(acc2[t2][mt][r] + b2v);
      }
  }
  __syncthreads();   // B8

  // ---------- LN2 + residual; direct bf16 store to sout ----------
  {
    int t2 = tid >> 3, oc = tid & 7;
    float v[32];
    float s1 = 0.f;
    #pragma unroll
    for (int b2 = 0; b2 < 4; ++b2) {
      s16x8 vb = *(const s16x8*)(sm + L_MB + t2 * 512 + swzb(t2, oc * 64 + b2 * 16));
      #pragma unroll
      for (int e = 0; e < 8; ++e) { float fv = bf2f((unsigned short)vb[e]); v[b2*8+e] = fv; s1 += fv; }
    }
    s1 += __shfl_xor(s1, 1);
    s1 += __shfl_xor(s1, 2);
    s1 += __shfl_xor(s1, 4);
    float mu = s1 * (1.f / 256.f);
    float s2 = 0.f;
    #pragma unroll
    for (int e = 0; e < 32; ++e) { float d = v[e] - mu; s2 += d * d; }
    s2 += __shfl_xor(s2, 1);
    s2 += __shfl_xor(s2, 2);
    s2 += __shfl_xor(s2, 4);
    float rs = __builtin_amdgcn_rsqf(s2 * (1.f / 256.f) + 1e-5f);
    int rp = (wi * 8 + (t2 >> 3) + 4) & 255;
    int cp = (wj * 8 + (t2 & 7) + 4) & 255;
    size_t pix = (size_t)bb * 65536 + rp * 256 + cp;
    unsigned short* so = sout + pix * 256 + oc * 32;
    #pragma unroll
    for (int b2 = 0; b2 < 4; ++b2) {
      s16x8 yb = *(const s16x8*)(sm + L_Y + t2 * 512 + swzb(t2, oc * 64 + b2 * 16));
      s16x8 pk;
      #pragma unroll
      for (int e = 0; e < 8; ++e) {
        int c = oc * 32 + b2 * 8 + e;
        float yv = (v[b2*8+e] - mu) * rs * ln2w[c] + ln2b[c] + bf2f((unsigned short)yb[e]);
        pk[e] = (short)f2bf(yv);
      }
      *(s16x8*)(so + b2 * 8) = pk;
    }
  }
}

extern "C" void kernel_launch(void* const* d_in, const int* in_sizes, int n_in,
                              void* d_out, int out_size, void* d_ws, size_t ws_size,
                              hipStream_t stream) {
  const float* x      = (const float*)d_in[0];
  const float* qkv_w  = (const float*)d_in[1];
  const float* ls     = (const float*)d_in[2];
  const float* proj_w = (const float*)d_in[3];
  const float* proj_b = (const float*)d_in[4];
  const float* ln1w   = (const float*)d_in[5];
  const float* ln1b   = (const float*)d_in[6];
  const float* fc1_w  = (const float*)d_in[7];
  const float* fc1b   = (const float*)d_in[8];
  const float* fc2_w  = (const float*)d_in[9];
  const float* fc2b   = (const float*)d_in[10];
  const float* ln2w   = (const float*)d_in[11];
  const float* ln2b   = (const float*)d_in[12];
  const float* cpb_w1 = (const float*)d_in[13];
  const float* cpb_b1 = (const float*)d_in[14];
  const float* cpb_w2 = (const float*)d_in[15];
  unsigned char* wsb = (unsigned char*)d_ws;
  float* out = (float*)d_out;

  hipFuncSetAttribute(reinterpret_cast<const void*>(swin_block_kernel),
                      hipFuncAttributeMaxDynamicSharedMemorySize, SMEM_BYTES);

  prep_kernel<<<11265, 256, 0, stream>>>(qkv_w, proj_w, fc1_w, fc2_w,
                                         cpb_w1, cpb_b1, cpb_w2, x, ls, wsb);
  swin_block_kernel<<<2048, 512, SMEM_BYTES, stream>>>(
      ls, proj_b, ln1w, ln1b, fc1b, fc2b, ln2w, ln2b, wsb);
  transpose_out_kernel<<<8192, 256, 0, stream>>>(wsb, out);
}